// Round 1
// baseline (2654.894 us; speedup 1.0000x reference)
//
#include <hip/hip_runtime.h>

// ---------------- problem constants ----------------
constexpr int L  = 6;
constexpr int C  = 512;
constexpr int FC = 2048;
constexpr int H  = 8;
constexpr int KC = 64;
constexpr int T  = 1024;
constexpr int B  = 4;
#define SCALE 0.125f   // 1/sqrt(KC)

typedef __bf16 bf16_t;
typedef __bf16 bf16x8 __attribute__((ext_vector_type(8)));
typedef float  f32x4  __attribute__((ext_vector_type(4)));

// ---------------- workspace layout (bytes) ----------------
// all offsets multiples of 4096
constexpr size_t OFF_XF    = 0;                               // f32 [B][T][C]      8 MB
constexpr size_t OFF_YF    = OFF_XF   + (size_t)B*T*C*4;      // f32 [B][T][C]      8 MB
constexpr size_t OFF_XPAD  = OFF_YF   + (size_t)B*T*C*4;      // bf16 [B][T+2][C]   4.01 MB
constexpr size_t OFF_Q     = OFF_XPAD + (size_t)B*(T+2)*C*2;  // bf16 [B][T][C]
constexpr size_t OFF_K     = OFF_Q    + (size_t)B*T*C*2;
constexpr size_t OFF_VT    = OFF_K    + (size_t)B*T*C*2;      // bf16 [B][C][T]
constexpr size_t OFF_YA    = OFF_VT   + (size_t)B*T*C*2;      // bf16 [B][T][C]
constexpr size_t OFF_MID   = OFF_YA   + (size_t)B*T*C*2;      // bf16 [B][T+2][FC]  16 MB
constexpr size_t OFF_WQKVO = OFF_MID  + (size_t)B*(T+2)*FC*2; // bf16 [4][C][C]
constexpr size_t OFF_W1    = OFF_WQKVO+ (size_t)4*C*C*2;      // bf16 [3][FC][C]
constexpr size_t OFF_W2    = OFF_W1   + (size_t)3*FC*C*2;     // bf16 [3][C][FC]
// total ~69.3 MB

// ---------------- conversion kernels ----------------
__global__ __launch_bounds__(256) void cvt4_kernel(const float* __restrict__ a,
                                                   const float* __restrict__ b,
                                                   const float* __restrict__ c,
                                                   const float* __restrict__ d,
                                                   bf16_t* __restrict__ out) {
    int i = blockIdx.x * 256 + threadIdx.x;      // 4*C*C = 4*2^18
    int which = i >> 18;
    int idx   = i & ((1 << 18) - 1);
    const float* s = (which == 0) ? a : (which == 1) ? b : (which == 2) ? c : d;
    out[i] = (bf16_t)s[idx];
}

__global__ __launch_bounds__(256) void cvtw1_kernel(const float* __restrict__ w1, bf16_t* __restrict__ out) {
    int i = blockIdx.x * 256 + threadIdx.x;      // FC*C*3
    int fc = i / (C * 3);
    int rem = i - fc * (C * 3);
    int c = rem / 3, j = rem - c * 3;
    out[(size_t)j * FC * C + (size_t)fc * C + c] = (bf16_t)w1[i];
}

__global__ __launch_bounds__(256) void cvtw2_kernel(const float* __restrict__ w2, bf16_t* __restrict__ out) {
    int i = blockIdx.x * 256 + threadIdx.x;      // C*FC*3
    int c = i / (FC * 3);
    int rem = i - c * (FC * 3);
    int fc = rem / 3, j = rem - fc * 3;
    out[(size_t)j * C * FC + (size_t)c * FC + fc] = (bf16_t)w2[i];
}

// ---------------- transpose in/out ----------------
__global__ __launch_bounds__(256) void transpose_in(const float* __restrict__ x0,
                                                    float* __restrict__ xf,
                                                    bf16_t* __restrict__ xpad) {
    __shared__ float tile[32][33];
    int b = blockIdx.z, t0 = blockIdx.x * 32, c0 = blockIdx.y * 32;
    int tx = threadIdx.x, ty = threadIdx.y;
#pragma unroll
    for (int j = 0; j < 4; ++j)
        tile[ty + j * 8][tx] = x0[((size_t)b * C + c0 + ty + j * 8) * T + t0 + tx];
    __syncthreads();
#pragma unroll
    for (int j = 0; j < 4; ++j) {
        float v = tile[tx][ty + j * 8];
        long t = t0 + ty + j * 8;
        xf[((size_t)b * T + t) * C + c0 + tx] = v;
        xpad[((size_t)b * (T + 2) + t + 1) * C + c0 + tx] = (bf16_t)v;
    }
}

__global__ __launch_bounds__(256) void transpose_out(const float* __restrict__ xf,
                                                     float* __restrict__ out) {
    __shared__ float tile[32][33];
    int b = blockIdx.z, t0 = blockIdx.x * 32, c0 = blockIdx.y * 32;
    int tx = threadIdx.x, ty = threadIdx.y;
#pragma unroll
    for (int j = 0; j < 4; ++j)
        tile[ty + j * 8][tx] = xf[((size_t)b * T + t0 + ty + j * 8) * C + c0 + tx];
    __syncthreads();
#pragma unroll
    for (int j = 0; j < 4; ++j)
        out[((size_t)b * C + c0 + ty + j * 8) * T + t0 + tx] = tile[tx][ty + j * 8];
}

// ---------------- zero conv pads ----------------
__global__ __launch_bounds__(256) void zero_pads(bf16_t* __restrict__ xpad, bf16_t* __restrict__ midp) {
    int i = blockIdx.x * 256 + threadIdx.x;   // 4096 + 16384 = 20480
    if (i < 4096) {
        int b = i >> 10, r = (i >> 9) & 1, c = i & 511;
        xpad[((size_t)b * (T + 2) + (size_t)r * (T + 1)) * C + c] = (bf16_t)0.f;
    } else {
        int j = i - 4096;
        int b = j >> 12, r = (j >> 11) & 1, c = j & 2047;
        midp[((size_t)b * (T + 2) + (size_t)r * (T + 1)) * FC + c] = (bf16_t)0.f;
    }
}

// ---------------- residual + layernorm (channel dim), writes f32 x and bf16 xpad ----------------
__global__ __launch_bounds__(256) void add_ln(float* __restrict__ x, const float* __restrict__ y,
                                              const float* __restrict__ g, const float* __restrict__ be,
                                              bf16_t* __restrict__ xpad) {
    long bt = blockIdx.x;      // b*T + t
    int tid = threadIdx.x;
    float* xr = x + bt * C;
    const float* yr = y + bt * C;
    float v0 = xr[tid] + yr[tid];
    float v1 = xr[tid + 256] + yr[tid + 256];
    float s = v0 + v1, q = v0 * v0 + v1 * v1;
#pragma unroll
    for (int m = 1; m < 64; m <<= 1) { s += __shfl_xor(s, m); q += __shfl_xor(q, m); }
    __shared__ float ss[4], qq[4];
    int wid = tid >> 6;
    if ((tid & 63) == 0) { ss[wid] = s; qq[wid] = q; }
    __syncthreads();
    s = ss[0] + ss[1] + ss[2] + ss[3];
    q = qq[0] + qq[1] + qq[2] + qq[3];
    float mean = s * (1.f / C);
    float var = q * (1.f / C) - mean * mean;
    float rstd = rsqrtf(var + 1e-4f);
    float o0 = (v0 - mean) * rstd * g[tid] + be[tid];
    float o1 = (v1 - mean) * rstd * g[tid + 256] + be[tid + 256];
    xr[tid] = o0; xr[tid + 256] = o1;
    long b = bt >> 10, t = bt & (T - 1);
    bf16_t* xp = xpad + (b * (T + 2) + t + 1) * C;
    xp[tid] = (bf16_t)o0; xp[tid + 256] = (bf16_t)o1;
}

// ---------------- TN GEMM: D[m][n] = sum_taps sum_k A[m+tap][k] * Bw[tap][n][k] + bias[n] ----------------
// OUTMODE: 0 = f32 [M][N], 1 = bf16 [M][N], 2 = bf16 transposed [N][M]
template <int BM, int OUTMODE, bool RELU>
__global__ __launch_bounds__(256) void gemm_tn(const bf16_t* __restrict__ A, long batchStrideA, int lda,
                                               const bf16_t* __restrict__ Bw, long tapStrideB, int ldb,
                                               const float* __restrict__ bias,
                                               void* __restrict__ Dv, long batchStrideD, int ldd,
                                               int Kdim, int ntaps) {
    constexpr int BK = 64;
    constexpr int MT = BM / 32;   // m-tiles (16 rows) per wave
    __shared__ bf16_t As[BM][72];
    __shared__ bf16_t Bs[128][72];
    const int tid = threadIdx.x;
    const int lane = tid & 63, wid = tid >> 6;
    const int l15 = lane & 15, quad = lane >> 4;
    const int wy = wid >> 1, wx = wid & 1;

    f32x4 acc[MT][4];
#pragma unroll
    for (int i = 0; i < MT; ++i)
#pragma unroll
        for (int j = 0; j < 4; ++j) acc[i][j] = (f32x4){0.f, 0.f, 0.f, 0.f};

    const bf16_t* Ab = A + (long)blockIdx.z * batchStrideA + (long)blockIdx.y * BM * lda;
    const bf16_t* Bb = Bw + (long)blockIdx.x * 128 * ldb;

    for (int tap = 0; tap < ntaps; ++tap) {
        const bf16_t* At = Ab + tap * lda;
        const bf16_t* Bt = Bb + (long)tap * tapStrideB;
        for (int k0 = 0; k0 < Kdim; k0 += BK) {
            __syncthreads();
#pragma unroll
            for (int i = 0; i < BM * 8 / 256; ++i) {
                int idx = tid + i * 256;
                int r = idx >> 3, c = idx & 7;
                *(uint4*)&As[r][c * 8] = *(const uint4*)(At + (long)r * lda + k0 + c * 8);
            }
#pragma unroll
            for (int i = 0; i < 4; ++i) {
                int idx = tid + i * 256;
                int r = idx >> 3, c = idx & 7;
                *(uint4*)&Bs[r][c * 8] = *(const uint4*)(Bt + (long)r * ldb + k0 + c * 8);
            }
            __syncthreads();
#pragma unroll
            for (int ks = 0; ks < 2; ++ks) {
                bf16x8 bfr[4];
#pragma unroll
                for (int nt = 0; nt < 4; ++nt)
                    bfr[nt] = *(const bf16x8*)&Bs[wx * 64 + nt * 16 + l15][ks * 32 + quad * 8];
#pragma unroll
                for (int mt = 0; mt < MT; ++mt) {
                    bf16x8 afr = *(const bf16x8*)&As[wy * (BM / 2) + mt * 16 + l15][ks * 32 + quad * 8];
#pragma unroll
                    for (int nt = 0; nt < 4; ++nt)
                        acc[mt][nt] = __builtin_amdgcn_mfma_f32_16x16x32_bf16(afr, bfr[nt], acc[mt][nt], 0, 0, 0);
                }
            }
        }
    }

    const long m0 = (long)blockIdx.y * BM + wy * (BM / 2);
    const int n0 = blockIdx.x * 128 + wx * 64;
#pragma unroll
    for (int mt = 0; mt < MT; ++mt) {
#pragma unroll
        for (int nt = 0; nt < 4; ++nt) {
            int col = n0 + nt * 16 + l15;
            float bb = bias[col];
            float v[4];
#pragma unroll
            for (int r = 0; r < 4; ++r) {
                v[r] = acc[mt][nt][r] + bb;
                if (RELU) v[r] = fmaxf(v[r], 0.f);
            }
            long rowb = m0 + mt * 16 + quad * 4;
            if (OUTMODE == 0) {
                float* D = (float*)Dv + (long)blockIdx.z * batchStrideD;
#pragma unroll
                for (int r = 0; r < 4; ++r) D[(rowb + r) * ldd + col] = v[r];
            } else if (OUTMODE == 1) {
                bf16_t* D = (bf16_t*)Dv + (long)blockIdx.z * batchStrideD;
#pragma unroll
                for (int r = 0; r < 4; ++r) D[(rowb + r) * ldd + col] = (bf16_t)v[r];
            } else {
                bf16_t* D = (bf16_t*)Dv + (long)blockIdx.z * batchStrideD;
                union { bf16_t h[4]; uint2 u; } pk;
#pragma unroll
                for (int r = 0; r < 4; ++r) pk.h[r] = (bf16_t)v[r];
                *(uint2*)(D + (long)col * ldd + rowb) = pk.u;
            }
        }
    }
}

// ---------------- fused attention (flash-style, rel-pos via 9 clamped embeddings) ----------------
// q,k: bf16 [B][T][C]; vT: bf16 [B][C][T]; relk: f32 [9][KC] (layer slice); y: bf16 [B][T][C]
__global__ __launch_bounds__(256) void attn_kernel(const bf16_t* __restrict__ q,
                                                   const bf16_t* __restrict__ k,
                                                   const bf16_t* __restrict__ vT,
                                                   const float* __restrict__ relk,
                                                   bf16_t* __restrict__ y) {
    const int b = blockIdx.z, h = blockIdx.y;
    const int qt0 = blockIdx.x * 128;
    __shared__ bf16_t qp[128][72];   // Q tile, reused as P tile
    __shared__ bf16_t kt[64][72];    // K tile [s][d]
    __shared__ bf16_t vt[64][72];    // V^T tile [d][s]
    __shared__ float  rl[128][12];   // rel logits per row, j=0..8

    const int tid = threadIdx.x;
    const int lane = tid & 63, wid = tid >> 6;
    const int l15 = lane & 15, quad = lane >> 4;

    // stage Q tile [128][64]
    const bf16_t* qbase = q + ((size_t)(b * T + qt0)) * C + h * 64;
#pragma unroll
    for (int i = 0; i < 4; ++i) {
        int idx = tid + i * 256;
        int r = idx >> 3, c = idx & 7;
        *(uint4*)&qp[r][c * 8] = *(const uint4*)(qbase + (long)r * C + c * 8);
    }
    __syncthreads();

    // rel logits: rl[row][j] = scale * q[row] . relk[j]
    for (int i = tid; i < 128 * 9; i += 256) {
        int r = i / 9, j = i - r * 9;
        float acc = 0.f;
#pragma unroll
        for (int d = 0; d < 64; ++d) acc += (float)qp[r][d] * relk[j * 64 + d];
        rl[r][j] = acc * SCALE;
    }

    // Q fragments (per-wave rows wid*32 .. wid*32+31)
    bf16x8 af[2][2];
#pragma unroll
    for (int mt = 0; mt < 2; ++mt)
#pragma unroll
        for (int ks = 0; ks < 2; ++ks)
            af[mt][ks] = *(const bf16x8*)&qp[wid * 32 + mt * 16 + l15][ks * 32 + quad * 8];

    float m_i[2][4], l_i[2][4];
    f32x4 o[2][4];
#pragma unroll
    for (int mt = 0; mt < 2; ++mt)
#pragma unroll
        for (int r = 0; r < 4; ++r) { m_i[mt][r] = -1e30f; l_i[mt][r] = 0.f; }
#pragma unroll
    for (int mt = 0; mt < 2; ++mt)
#pragma unroll
        for (int dn = 0; dn < 4; ++dn) o[mt][dn] = (f32x4){0.f, 0.f, 0.f, 0.f};

    for (int st = 0; st < T / 64; ++st) {
        __syncthreads();   // protect kt/vt (prev iter reads) and, at st=0, qp/rl init phase
        const bf16_t* kb = k + ((size_t)(b * T + st * 64)) * C + h * 64;
        const bf16_t* vb = vT + ((size_t)(b * C + h * 64)) * T + st * 64;
#pragma unroll
        for (int i = 0; i < 2; ++i) {
            int idx = tid + i * 256;
            int r = idx >> 3, c = idx & 7;
            *(uint4*)&kt[r][c * 8] = *(const uint4*)(kb + (long)r * C + c * 8);
        }
#pragma unroll
        for (int i = 0; i < 2; ++i) {
            int idx = tid + i * 256;
            int r = idx >> 3, c = idx & 7;
            *(uint4*)&vt[r][c * 8] = *(const uint4*)(vb + (long)r * T + c * 8);
        }
        __syncthreads();

        // scores: per wave 32x64 = 2 m-tiles x 4 n-tiles
        f32x4 sc4[2][4];
#pragma unroll
        for (int mt = 0; mt < 2; ++mt)
#pragma unroll
            for (int nt = 0; nt < 4; ++nt) {
                f32x4 a = (f32x4){0.f, 0.f, 0.f, 0.f};
#pragma unroll
                for (int ks = 0; ks < 2; ++ks) {
                    bf16x8 bfr = *(const bf16x8*)&kt[nt * 16 + l15][ks * 32 + quad * 8];
                    a = __builtin_amdgcn_mfma_f32_16x16x32_bf16(af[mt][ks], bfr, a, 0, 0, 0);
                }
                sc4[mt][nt] = a;
            }

        // scale + rel bias
#pragma unroll
        for (int mt = 0; mt < 2; ++mt)
#pragma unroll
            for (int nt = 0; nt < 4; ++nt)
#pragma unroll
                for (int r = 0; r < 4; ++r) {
                    int row = wid * 32 + mt * 16 + quad * 4 + r;
                    int tpos = qt0 + row;
                    int spos = st * 64 + nt * 16 + l15;
                    int j = spos - tpos + 4;
                    j = j < 0 ? 0 : (j > 8 ? 8 : j);
                    sc4[mt][nt][r] = sc4[mt][nt][r] * SCALE + rl[row][j];
                }

        // online softmax
        float alpha[2][4];
#pragma unroll
        for (int mt = 0; mt < 2; ++mt)
#pragma unroll
            for (int r = 0; r < 4; ++r) {
                float mx = fmaxf(fmaxf(sc4[mt][0][r], sc4[mt][1][r]), fmaxf(sc4[mt][2][r], sc4[mt][3][r]));
#pragma unroll
                for (int d = 1; d < 16; d <<= 1) mx = fmaxf(mx, __shfl_xor(mx, d));
                float mn = fmaxf(m_i[mt][r], mx);
                alpha[mt][r] = __expf(m_i[mt][r] - mn);
                m_i[mt][r] = mn;
            }
#pragma unroll
        for (int mt = 0; mt < 2; ++mt)
#pragma unroll
            for (int r = 0; r < 4; ++r) {
                float rs = 0.f;
#pragma unroll
                for (int nt = 0; nt < 4; ++nt) {
                    float p = __expf(sc4[mt][nt][r] - m_i[mt][r]);
                    sc4[mt][nt][r] = p;
                    rs += p;
                }
#pragma unroll
                for (int d = 1; d < 16; d <<= 1) rs += __shfl_xor(rs, d);
                l_i[mt][r] = l_i[mt][r] * alpha[mt][r] + rs;
            }
#pragma unroll
        for (int mt = 0; mt < 2; ++mt)
#pragma unroll
            for (int dn = 0; dn < 4; ++dn)
#pragma unroll
                for (int r = 0; r < 4; ++r) o[mt][dn][r] *= alpha[mt][r];

        // write P into LDS (wave-private rows), then PV MFMA
#pragma unroll
        for (int mt = 0; mt < 2; ++mt)
#pragma unroll
            for (int nt = 0; nt < 4; ++nt)
#pragma unroll
                for (int r = 0; r < 4; ++r)
                    qp[wid * 32 + mt * 16 + quad * 4 + r][nt * 16 + l15] = (bf16_t)sc4[mt][nt][r];

#pragma unroll
        for (int mt = 0; mt < 2; ++mt) {
            bf16x8 pa[2];
#pragma unroll
            for (int ks = 0; ks < 2; ++ks)
                pa[ks] = *(const bf16x8*)&qp[wid * 32 + mt * 16 + l15][ks * 32 + quad * 8];
#pragma unroll
            for (int dn = 0; dn < 4; ++dn)
#pragma unroll
                for (int ks = 0; ks < 2; ++ks) {
                    bf16x8 vf = *(const bf16x8*)&vt[dn * 16 + l15][ks * 32 + quad * 8];
                    o[mt][dn] = __builtin_amdgcn_mfma_f32_16x16x32_bf16(pa[ks], vf, o[mt][dn], 0, 0, 0);
                }
        }
    }

    // epilogue: O / l -> y [T][C]
    bf16_t* yb = y + ((size_t)(b * T + qt0)) * C + h * 64;
#pragma unroll
    for (int mt = 0; mt < 2; ++mt)
#pragma unroll
        for (int r = 0; r < 4; ++r) {
            float linv = 1.f / l_i[mt][r];
            int row = wid * 32 + mt * 16 + quad * 4 + r;
#pragma unroll
            for (int dn = 0; dn < 4; ++dn)
                yb[(long)row * C + dn * 16 + l15] = (bf16_t)(o[mt][dn][r] * linv);
        }
}

// ---------------- host launch ----------------
extern "C" void kernel_launch(void* const* d_in, const int* in_sizes, int n_in,
                              void* d_out, int out_size, void* d_ws, size_t ws_size,
                              hipStream_t stream) {
    const float* x0  = (const float*)d_in[0];
    const float* wq  = (const float*)d_in[1];
    const float* bq  = (const float*)d_in[2];
    const float* wk  = (const float*)d_in[3];
    const float* bk  = (const float*)d_in[4];
    const float* wv  = (const float*)d_in[5];
    const float* bv  = (const float*)d_in[6];
    const float* wo  = (const float*)d_in[7];
    const float* bo  = (const float*)d_in[8];
    const float* rlk = (const float*)d_in[9];
    const float* g1  = (const float*)d_in[10];
    const float* be1 = (const float*)d_in[11];
    const float* w1  = (const float*)d_in[12];
    const float* bb1 = (const float*)d_in[13];
    const float* w2  = (const float*)d_in[14];
    const float* bb2 = (const float*)d_in[15];
    const float* g2  = (const float*)d_in[16];
    const float* be2 = (const float*)d_in[17];

    char* ws = (char*)d_ws;
    float*  xf    = (float*)(ws + OFF_XF);
    float*  yf    = (float*)(ws + OFF_YF);
    bf16_t* xpad  = (bf16_t*)(ws + OFF_XPAD);
    bf16_t* qb    = (bf16_t*)(ws + OFF_Q);
    bf16_t* kb    = (bf16_t*)(ws + OFF_K);
    bf16_t* vTb   = (bf16_t*)(ws + OFF_VT);
    bf16_t* yab   = (bf16_t*)(ws + OFF_YA);
    bf16_t* midp  = (bf16_t*)(ws + OFF_MID);
    bf16_t* wqkvo = (bf16_t*)(ws + OFF_WQKVO);
    bf16_t* w1b   = (bf16_t*)(ws + OFF_W1);
    bf16_t* w2b   = (bf16_t*)(ws + OFF_W2);

    transpose_in<<<dim3(T / 32, C / 32, B), dim3(32, 8), 0, stream>>>(x0, xf, xpad);
    zero_pads<<<80, 256, 0, stream>>>(xpad, midp);

    for (int l = 0; l < L; ++l) {
        cvt4_kernel<<<4 * C * C / 256, 256, 0, stream>>>(wq + (size_t)l * C * C, wk + (size_t)l * C * C,
                                                         wv + (size_t)l * C * C, wo + (size_t)l * C * C, wqkvo);
        cvtw1_kernel<<<FC * C * 3 / 256, 256, 0, stream>>>(w1 + (size_t)l * FC * C * 3, w1b);
        cvtw2_kernel<<<C * FC * 3 / 256, 256, 0, stream>>>(w2 + (size_t)l * C * FC * 3, w2b);

        // Q, K projections -> bf16 [B][T][C]
        gemm_tn<64, 1, false><<<dim3(C / 128, T / 64, B), 256, 0, stream>>>(
            xpad + C, (long)(T + 2) * C, C, wqkvo, 0, C, bq + l * C,
            (void*)qb, (long)T * C, C, C, 1);
        gemm_tn<64, 1, false><<<dim3(C / 128, T / 64, B), 256, 0, stream>>>(
            xpad + C, (long)(T + 2) * C, C, wqkvo + C * C, 0, C, bk + l * C,
            (void*)kb, (long)T * C, C, C, 1);
        // V projection -> transposed bf16 [B][C][T]
        gemm_tn<64, 2, false><<<dim3(C / 128, T / 64, B), 256, 0, stream>>>(
            xpad + C, (long)(T + 2) * C, C, wqkvo + 2 * C * C, 0, C, bv + l * C,
            (void*)vTb, (long)C * T, T, C, 1);

        attn_kernel<<<dim3(T / 128, H, B), 256, 0, stream>>>(qb, kb, vTb, rlk + (size_t)l * 9 * KC, yab);

        // O projection -> f32 [B][T][C]
        gemm_tn<64, 0, false><<<dim3(C / 128, T / 64, B), 256, 0, stream>>>(
            yab, (long)T * C, C, wqkvo + 3 * C * C, 0, C, bo + l * C,
            (void*)yf, (long)T * C, C, C, 1);

        add_ln<<<B * T, 256, 0, stream>>>(xf, yf, g1 + l * C, be1 + l * C, xpad);

        // FFN1: conv K=3 + bias + relu -> bf16 mid_pad rows 1..T
        gemm_tn<128, 1, true><<<dim3(FC / 128, T / 128, B), 256, 0, stream>>>(
            xpad, (long)(T + 2) * C, C, w1b, (long)FC * C, C, bb1 + l * FC,
            (void*)(midp + FC), (long)(T + 2) * FC, FC, C, 3);
        // FFN2: conv K=3 + bias -> f32 [B][T][C]
        gemm_tn<64, 0, false><<<dim3(C / 128, T / 64, B), 256, 0, stream>>>(
            midp, (long)(T + 2) * FC, FC, w2b, (long)C * FC, FC, bb2 + l * C,
            (void*)yf, (long)T * C, C, FC, 3);

        add_ln<<<B * T, 256, 0, stream>>>(xf, yf, g2 + l * C, be2 + l * C, xpad);
    }

    transpose_out<<<dim3(T / 32, C / 32, B), dim3(32, 8), 0, stream>>>(xf, (float*)d_out);
}

// Round 2
// 1543.400 us; speedup vs baseline: 1.7202x; 1.7202x over previous
//
#include <hip/hip_runtime.h>

// ---------------- problem constants ----------------
constexpr int L  = 6;
constexpr int C  = 512;
constexpr int FC = 2048;
constexpr int H  = 8;
constexpr int KC = 64;
constexpr int T  = 1024;
constexpr int B  = 4;
#define SCALE 0.125f   // 1/sqrt(KC)

typedef __bf16 bf16_t;
typedef __bf16 bf16x8 __attribute__((ext_vector_type(8)));
typedef float  f32x4  __attribute__((ext_vector_type(4)));

// ---------------- workspace layout (bytes) ----------------
constexpr size_t OFF_XF    = 0;                               // f32 [B][T][C]      8 MB
constexpr size_t OFF_YF    = OFF_XF   + (size_t)B*T*C*4;      // f32 [B][T][C]      8 MB (split-0 partial)
constexpr size_t OFF_XPAD  = OFF_YF   + (size_t)B*T*C*4;      // bf16 [B][T+2][C]
constexpr size_t OFF_Q     = OFF_XPAD + (size_t)B*(T+2)*C*2;  // bf16 [B][T][C]  (aliased: f32 split-1 partial, 8MB spans Q+K)
constexpr size_t OFF_K     = OFF_Q    + (size_t)B*T*C*2;
constexpr size_t OFF_VT    = OFF_K    + (size_t)B*T*C*2;      // bf16 [B][C][T]
constexpr size_t OFF_YA    = OFF_VT   + (size_t)B*T*C*2;      // bf16 [B][T][C]
constexpr size_t OFF_MID   = OFF_YA   + (size_t)B*T*C*2;      // bf16 [B][T+2][FC]  16 MB
constexpr size_t OFF_WQKVO = OFF_MID  + (size_t)B*(T+2)*FC*2; // bf16 [4][C][C]  (wq|wk|wv|wo rows)
constexpr size_t OFF_W1    = OFF_WQKVO+ (size_t)4*C*C*2;      // bf16 [3][FC][C]
constexpr size_t OFF_W2    = OFF_W1   + (size_t)3*FC*C*2;     // bf16 [3][C][FC]
// total ~69.3 MB

// ---------------- async global->LDS (16B/lane) ----------------
__device__ __forceinline__ void gload_lds16(const bf16_t* g, bf16_t* l) {
    __builtin_amdgcn_global_load_lds((const __attribute__((address_space(1))) void*)g,
                                     (__attribute__((address_space(3))) void*)l, 16, 0, 0);
}

// ---------------- conversion kernels ----------------
__global__ __launch_bounds__(256) void cvt4_kernel(const float* __restrict__ a,
                                                   const float* __restrict__ b,
                                                   const float* __restrict__ c,
                                                   const float* __restrict__ d,
                                                   bf16_t* __restrict__ out) {
    int i = blockIdx.x * 256 + threadIdx.x;      // 4*C*C = 4*2^18
    int which = i >> 18;
    int idx   = i & ((1 << 18) - 1);
    const float* s = (which == 0) ? a : (which == 1) ? b : (which == 2) ? c : d;
    out[i] = (bf16_t)s[idx];
}

__global__ __launch_bounds__(256) void cvtw1_kernel(const float* __restrict__ w1, bf16_t* __restrict__ out) {
    int i = blockIdx.x * 256 + threadIdx.x;      // FC*C*3
    int fc = i / (C * 3);
    int rem = i - fc * (C * 3);
    int c = rem / 3, j = rem - c * 3;
    out[(size_t)j * FC * C + (size_t)fc * C + c] = (bf16_t)w1[i];
}

__global__ __launch_bounds__(256) void cvtw2_kernel(const float* __restrict__ w2, bf16_t* __restrict__ out) {
    int i = blockIdx.x * 256 + threadIdx.x;      // C*FC*3
    int c = i / (FC * 3);
    int rem = i - c * (FC * 3);
    int fc = rem / 3, j = rem - fc * 3;
    out[(size_t)j * C * FC + (size_t)c * FC + fc] = (bf16_t)w2[i];
}

// ---------------- transpose in/out ----------------
__global__ __launch_bounds__(256) void transpose_in(const float* __restrict__ x0,
                                                    float* __restrict__ xf,
                                                    bf16_t* __restrict__ xpad) {
    __shared__ float tile[32][33];
    int b = blockIdx.z, t0 = blockIdx.x * 32, c0 = blockIdx.y * 32;
    int tx = threadIdx.x, ty = threadIdx.y;
#pragma unroll
    for (int j = 0; j < 4; ++j)
        tile[ty + j * 8][tx] = x0[((size_t)b * C + c0 + ty + j * 8) * T + t0 + tx];
    __syncthreads();
#pragma unroll
    for (int j = 0; j < 4; ++j) {
        float v = tile[tx][ty + j * 8];
        long t = t0 + ty + j * 8;
        xf[((size_t)b * T + t) * C + c0 + tx] = v;
        xpad[((size_t)b * (T + 2) + t + 1) * C + c0 + tx] = (bf16_t)v;
    }
}

__global__ __launch_bounds__(256) void transpose_out(const float* __restrict__ xf,
                                                     float* __restrict__ out) {
    __shared__ float tile[32][33];
    int b = blockIdx.z, t0 = blockIdx.x * 32, c0 = blockIdx.y * 32;
    int tx = threadIdx.x, ty = threadIdx.y;
#pragma unroll
    for (int j = 0; j < 4; ++j)
        tile[ty + j * 8][tx] = xf[((size_t)b * T + t0 + ty + j * 8) * C + c0 + tx];
    __syncthreads();
#pragma unroll
    for (int j = 0; j < 4; ++j)
        out[((size_t)b * C + c0 + ty + j * 8) * T + t0 + tx] = tile[tx][ty + j * 8];
}

// ---------------- zero conv pads ----------------
__global__ __launch_bounds__(256) void zero_pads(bf16_t* __restrict__ xpad, bf16_t* __restrict__ midp) {
    int i = blockIdx.x * 256 + threadIdx.x;   // 4096 + 16384 = 20480
    if (i < 4096) {
        int b = i >> 10, r = (i >> 9) & 1, c = i & 511;
        xpad[((size_t)b * (T + 2) + (size_t)r * (T + 1)) * C + c] = (bf16_t)0.f;
    } else {
        int j = i - 4096;
        int b = j >> 12, r = (j >> 11) & 1, c = j & 2047;
        midp[((size_t)b * (T + 2) + (size_t)r * (T + 1)) * FC + c] = (bf16_t)0.f;
    }
}

// ---------------- residual + 2-partial sum + layernorm (channel dim) ----------------
__global__ __launch_bounds__(256) void add_ln(float* __restrict__ x,
                                              const float* __restrict__ p0, const float* __restrict__ p1,
                                              const float* __restrict__ g, const float* __restrict__ be,
                                              bf16_t* __restrict__ xpad) {
    long bt = blockIdx.x;      // b*T + t
    int tid = threadIdx.x;
    float* xr = x + bt * C;
    const float* p0r = p0 + bt * C;
    const float* p1r = p1 + bt * C;
    float v0 = xr[tid] + p0r[tid] + p1r[tid];
    float v1 = xr[tid + 256] + p0r[tid + 256] + p1r[tid + 256];
    float s = v0 + v1, q = v0 * v0 + v1 * v1;
#pragma unroll
    for (int m = 1; m < 64; m <<= 1) { s += __shfl_xor(s, m); q += __shfl_xor(q, m); }
    __shared__ float ss[4], qq[4];
    int wid = tid >> 6;
    if ((tid & 63) == 0) { ss[wid] = s; qq[wid] = q; }
    __syncthreads();
    s = ss[0] + ss[1] + ss[2] + ss[3];
    q = qq[0] + qq[1] + qq[2] + qq[3];
    float mean = s * (1.f / C);
    float var = q * (1.f / C) - mean * mean;
    float rstd = rsqrtf(var + 1e-4f);
    float o0 = (v0 - mean) * rstd * g[tid] + be[tid];
    float o1 = (v1 - mean) * rstd * g[tid + 256] + be[tid + 256];
    xr[tid] = o0; xr[tid + 256] = o1;
    long b = bt >> 10, t = bt & (T - 1);
    bf16_t* xp = xpad + (b * (T + 2) + t + 1) * C;
    xp[tid] = (bf16_t)o0; xp[tid + 256] = (bf16_t)o1;
}

// ---------------- m97-style 128x128 GEMM, BK=64, global_load_lds staging ----------------
// D[m][n] = sum_taps sum_k A[m+tap][k] * Bw[tap][n][k] (+bias)
// OUTMODE: 0 = f32 [M][N] split-partial (split0->Dp +bias, split1->D1p raw)
//          1 = bf16 [M][N] (+bias, opt relu)
//          3 = QKV fused: col<512 -> Q (Dp), <1024 -> K (D1p), else V^T (D2p)
template <int OUTMODE, bool RELU, int NSPLIT, int IPT, int NTAPS>
__global__ __launch_bounds__(256) void gemm128(
    const bf16_t* __restrict__ A, long batchStrideA, int lda,
    const bf16_t* __restrict__ Bw, long tapStrideB, int ldb,
    const float* __restrict__ bias0, const float* __restrict__ bias1,
    const float* __restrict__ bias2,
    void* __restrict__ Dp, void* __restrict__ D1p, void* __restrict__ D2p,
    long batchStrideD, int ldd) {
    __shared__ bf16_t As[128 * 64];
    __shared__ bf16_t Bs[128 * 64];
    const int tid = threadIdx.x;
    const int lane = tid & 63, wid = tid >> 6;
    const int l15 = lane & 15, quad = lane >> 4;
    const int wy = wid >> 1, wx = wid & 1;
    const int nb = gridDim.z / NSPLIT;
    const int split = (NSPLIT > 1) ? ((int)blockIdx.z / nb) : 0;
    const int b = (int)blockIdx.z - split * nb;

    const bf16_t* Ab = A + (long)b * batchStrideA + (long)blockIdx.y * 128 * lda;
    const bf16_t* Bb = Bw + (long)blockIdx.x * 128 * ldb;

    const int lrow = lane >> 3;          // row within 8-row chunk
    const int lcol = (lane & 7) * 8;     // bf16 col offset

    f32x4 acc[4][4];
#pragma unroll
    for (int i = 0; i < 4; ++i)
#pragma unroll
        for (int j = 0; j < 4; ++j) acc[i][j] = (f32x4){0.f, 0.f, 0.f, 0.f};

    constexpr int itersAll = IPT * NTAPS;
    constexpr int per = itersAll / NSPLIT;
    const int it0 = split * per;

    for (int it = it0; it < it0 + per; ++it) {
        const int tap = (NTAPS == 1) ? 0 : (it / IPT);
        const int k0 = (it - tap * IPT) * 64;
        const bf16_t* At = Ab + (long)tap * lda + k0;
        const bf16_t* Bt = Bb + (long)tap * tapStrideB + k0;
        __syncthreads();
#pragma unroll
        for (int i = 0; i < 4; ++i) {
            int chunk = wid * 4 + i;
            int row = chunk * 8 + lrow;
            gload_lds16(At + (long)row * lda + lcol, As + chunk * 512 + lane * 8);
            gload_lds16(Bt + (long)row * ldb + lcol, Bs + chunk * 512 + lane * 8);
        }
        __syncthreads();
#pragma unroll
        for (int ks = 0; ks < 2; ++ks) {
            bf16x8 bfr[4], afr[4];
#pragma unroll
            for (int nt = 0; nt < 4; ++nt)
                bfr[nt] = *(const bf16x8*)&Bs[(wx * 64 + nt * 16 + l15) * 64 + ks * 32 + quad * 8];
#pragma unroll
            for (int mt = 0; mt < 4; ++mt)
                afr[mt] = *(const bf16x8*)&As[(wy * 64 + mt * 16 + l15) * 64 + ks * 32 + quad * 8];
#pragma unroll
            for (int mt = 0; mt < 4; ++mt)
#pragma unroll
                for (int nt = 0; nt < 4; ++nt)
                    acc[mt][nt] = __builtin_amdgcn_mfma_f32_16x16x32_bf16(afr[mt], bfr[nt], acc[mt][nt], 0, 0, 0);
        }
    }

    const long m0 = (long)blockIdx.y * 128 + wy * 64;
    const int n0g = (int)blockIdx.x * 128 + wx * 64;
#pragma unroll
    for (int mt = 0; mt < 4; ++mt) {
        long rowb = m0 + mt * 16 + quad * 4;
#pragma unroll
        for (int nt = 0; nt < 4; ++nt) {
            int col = n0g + nt * 16 + l15;
            if (OUTMODE == 0) {
                float bb = (split == 0) ? bias0[col] : 0.f;
                float* D = ((split == 0) ? (float*)Dp : (float*)D1p) + (long)b * batchStrideD;
#pragma unroll
                for (int r = 0; r < 4; ++r) D[(rowb + r) * ldd + col] = acc[mt][nt][r] + bb;
            } else if (OUTMODE == 1) {
                float bb = bias0[col];
                bf16_t* D = (bf16_t*)Dp + (long)b * batchStrideD;
#pragma unroll
                for (int r = 0; r < 4; ++r) {
                    float v = acc[mt][nt][r] + bb;
                    if (RELU) v = fmaxf(v, 0.f);
                    D[(rowb + r) * ldd + col] = (bf16_t)v;
                }
            } else {  // QKV fused
                int which = col >> 9, cl = col & 511;
                const float* bp = (which == 0) ? bias0 : (which == 1) ? bias1 : bias2;
                float bb = bp[cl];
                if (which < 2) {
                    bf16_t* D = (bf16_t*)((which == 0) ? Dp : D1p) + (long)b * T * C;
#pragma unroll
                    for (int r = 0; r < 4; ++r) D[(rowb + r) * C + cl] = (bf16_t)(acc[mt][nt][r] + bb);
                } else {
                    bf16_t* D = (bf16_t*)D2p + (long)b * C * T;
                    union { bf16_t h[4]; uint2 u; } pk;
#pragma unroll
                    for (int r = 0; r < 4; ++r) pk.h[r] = (bf16_t)(acc[mt][nt][r] + bb);
                    *(uint2*)(D + (long)cl * T + rowb) = pk.u;
                }
            }
        }
    }
}

// ---------------- fused attention (flash-style, rel-pos via 9 clamped embeddings) ----------------
__global__ __launch_bounds__(256) void attn_kernel(const bf16_t* __restrict__ q,
                                                   const bf16_t* __restrict__ k,
                                                   const bf16_t* __restrict__ vT,
                                                   const float* __restrict__ relk,
                                                   bf16_t* __restrict__ y) {
    const int b = blockIdx.z, h = blockIdx.y;
    const int qt0 = blockIdx.x * 128;
    __shared__ bf16_t qp[128][72];   // Q tile, reused as P tile
    __shared__ bf16_t kt[64][72];    // K tile [s][d]
    __shared__ bf16_t vt[64][72];    // V^T tile [d][s]
    __shared__ float  rl[128][12];   // rel logits per row, j=0..8

    const int tid = threadIdx.x;
    const int lane = tid & 63, wid = tid >> 6;
    const int l15 = lane & 15, quad = lane >> 4;

    const bf16_t* qbase = q + ((size_t)(b * T + qt0)) * C + h * 64;
#pragma unroll
    for (int i = 0; i < 4; ++i) {
        int idx = tid + i * 256;
        int r = idx >> 3, c = idx & 7;
        *(uint4*)&qp[r][c * 8] = *(const uint4*)(qbase + (long)r * C + c * 8);
    }
    __syncthreads();

    for (int i = tid; i < 128 * 9; i += 256) {
        int r = i / 9, j = i - r * 9;
        float acc = 0.f;
#pragma unroll
        for (int d = 0; d < 64; ++d) acc += (float)qp[r][d] * relk[j * 64 + d];
        rl[r][j] = acc * SCALE;
    }

    bf16x8 af[2][2];
#pragma unroll
    for (int mt = 0; mt < 2; ++mt)
#pragma unroll
        for (int ks = 0; ks < 2; ++ks)
            af[mt][ks] = *(const bf16x8*)&qp[wid * 32 + mt * 16 + l15][ks * 32 + quad * 8];

    float m_i[2][4], l_i[2][4];
    f32x4 o[2][4];
#pragma unroll
    for (int mt = 0; mt < 2; ++mt)
#pragma unroll
        for (int r = 0; r < 4; ++r) { m_i[mt][r] = -1e30f; l_i[mt][r] = 0.f; }
#pragma unroll
    for (int mt = 0; mt < 2; ++mt)
#pragma unroll
        for (int dn = 0; dn < 4; ++dn) o[mt][dn] = (f32x4){0.f, 0.f, 0.f, 0.f};

    for (int st = 0; st < T / 64; ++st) {
        __syncthreads();
        const bf16_t* kb = k + ((size_t)(b * T + st * 64)) * C + h * 64;
        const bf16_t* vb = vT + ((size_t)(b * C + h * 64)) * T + st * 64;
#pragma unroll
        for (int i = 0; i < 2; ++i) {
            int idx = tid + i * 256;
            int r = idx >> 3, c = idx & 7;
            *(uint4*)&kt[r][c * 8] = *(const uint4*)(kb + (long)r * C + c * 8);
        }
#pragma unroll
        for (int i = 0; i < 2; ++i) {
            int idx = tid + i * 256;
            int r = idx >> 3, c = idx & 7;
            *(uint4*)&vt[r][c * 8] = *(const uint4*)(vb + (long)r * T + c * 8);
        }
        __syncthreads();

        f32x4 sc4[2][4];
#pragma unroll
        for (int mt = 0; mt < 2; ++mt)
#pragma unroll
            for (int nt = 0; nt < 4; ++nt) {
                f32x4 a = (f32x4){0.f, 0.f, 0.f, 0.f};
#pragma unroll
                for (int ks = 0; ks < 2; ++ks) {
                    bf16x8 bfr = *(const bf16x8*)&kt[nt * 16 + l15][ks * 32 + quad * 8];
                    a = __builtin_amdgcn_mfma_f32_16x16x32_bf16(af[mt][ks], bfr, a, 0, 0, 0);
                }
                sc4[mt][nt] = a;
            }

#pragma unroll
        for (int mt = 0; mt < 2; ++mt)
#pragma unroll
            for (int nt = 0; nt < 4; ++nt)
#pragma unroll
                for (int r = 0; r < 4; ++r) {
                    int row = wid * 32 + mt * 16 + quad * 4 + r;
                    int tpos = qt0 + row;
                    int spos = st * 64 + nt * 16 + l15;
                    int j = spos - tpos + 4;
                    j = j < 0 ? 0 : (j > 8 ? 8 : j);
                    sc4[mt][nt][r] = sc4[mt][nt][r] * SCALE + rl[row][j];
                }

        float alpha[2][4];
#pragma unroll
        for (int mt = 0; mt < 2; ++mt)
#pragma unroll
            for (int r = 0; r < 4; ++r) {
                float mx = fmaxf(fmaxf(sc4[mt][0][r], sc4[mt][1][r]), fmaxf(sc4[mt][2][r], sc4[mt][3][r]));
#pragma unroll
                for (int d = 1; d < 16; d <<= 1) mx = fmaxf(mx, __shfl_xor(mx, d));
                float mn = fmaxf(m_i[mt][r], mx);
                alpha[mt][r] = __expf(m_i[mt][r] - mn);
                m_i[mt][r] = mn;
            }
#pragma unroll
        for (int mt = 0; mt < 2; ++mt)
#pragma unroll
            for (int r = 0; r < 4; ++r) {
                float rs = 0.f;
#pragma unroll
                for (int nt = 0; nt < 4; ++nt) {
                    float p = __expf(sc4[mt][nt][r] - m_i[mt][r]);
                    sc4[mt][nt][r] = p;
                    rs += p;
                }
#pragma unroll
                for (int d = 1; d < 16; d <<= 1) rs += __shfl_xor(rs, d);
                l_i[mt][r] = l_i[mt][r] * alpha[mt][r] + rs;
            }
#pragma unroll
        for (int mt = 0; mt < 2; ++mt)
#pragma unroll
            for (int dn = 0; dn < 4; ++dn)
#pragma unroll
                for (int r = 0; r < 4; ++r) o[mt][dn][r] *= alpha[mt][r];

#pragma unroll
        for (int mt = 0; mt < 2; ++mt)
#pragma unroll
            for (int nt = 0; nt < 4; ++nt)
#pragma unroll
                for (int r = 0; r < 4; ++r)
                    qp[wid * 32 + mt * 16 + quad * 4 + r][nt * 16 + l15] = (bf16_t)sc4[mt][nt][r];

#pragma unroll
        for (int mt = 0; mt < 2; ++mt) {
            bf16x8 pa[2];
#pragma unroll
            for (int ks = 0; ks < 2; ++ks)
                pa[ks] = *(const bf16x8*)&qp[wid * 32 + mt * 16 + l15][ks * 32 + quad * 8];
#pragma unroll
            for (int dn = 0; dn < 4; ++dn)
#pragma unroll
                for (int ks = 0; ks < 2; ++ks) {
                    bf16x8 vf = *(const bf16x8*)&vt[dn * 16 + l15][ks * 32 + quad * 8];
                    o[mt][dn] = __builtin_amdgcn_mfma_f32_16x16x32_bf16(pa[ks], vf, o[mt][dn], 0, 0, 0);
                }
        }
    }

    bf16_t* yb = y + ((size_t)(b * T + qt0)) * C + h * 64;
#pragma unroll
    for (int mt = 0; mt < 2; ++mt)
#pragma unroll
        for (int r = 0; r < 4; ++r) {
            float linv = 1.f / l_i[mt][r];
            int row = wid * 32 + mt * 16 + quad * 4 + r;
#pragma unroll
            for (int dn = 0; dn < 4; ++dn)
                yb[(long)row * C + dn * 16 + l15] = (bf16_t)(o[mt][dn][r] * linv);
        }
}

// ---------------- host launch ----------------
extern "C" void kernel_launch(void* const* d_in, const int* in_sizes, int n_in,
                              void* d_out, int out_size, void* d_ws, size_t ws_size,
                              hipStream_t stream) {
    const float* x0  = (const float*)d_in[0];
    const float* wq  = (const float*)d_in[1];
    const float* bq  = (const float*)d_in[2];
    const float* wk  = (const float*)d_in[3];
    const float* bk  = (const float*)d_in[4];
    const float* wv  = (const float*)d_in[5];
    const float* bv  = (const float*)d_in[6];
    const float* wo  = (const float*)d_in[7];
    const float* bo  = (const float*)d_in[8];
    const float* rlk = (const float*)d_in[9];
    const float* g1  = (const float*)d_in[10];
    const float* be1 = (const float*)d_in[11];
    const float* w1  = (const float*)d_in[12];
    const float* bb1 = (const float*)d_in[13];
    const float* w2  = (const float*)d_in[14];
    const float* bb2 = (const float*)d_in[15];
    const float* g2  = (const float*)d_in[16];
    const float* be2 = (const float*)d_in[17];

    char* ws = (char*)d_ws;
    float*  xf    = (float*)(ws + OFF_XF);
    float*  yf    = (float*)(ws + OFF_YF);
    float*  yf2   = (float*)(ws + OFF_Q);       // aliases Q+K buffers (dead at use time)
    bf16_t* xpad  = (bf16_t*)(ws + OFF_XPAD);
    bf16_t* qb    = (bf16_t*)(ws + OFF_Q);
    bf16_t* kb    = (bf16_t*)(ws + OFF_K);
    bf16_t* vTb   = (bf16_t*)(ws + OFF_VT);
    bf16_t* yab   = (bf16_t*)(ws + OFF_YA);
    bf16_t* midp  = (bf16_t*)(ws + OFF_MID);
    bf16_t* wqkvo = (bf16_t*)(ws + OFF_WQKVO);
    bf16_t* w1b   = (bf16_t*)(ws + OFF_W1);
    bf16_t* w2b   = (bf16_t*)(ws + OFF_W2);

    transpose_in<<<dim3(T / 32, C / 32, B), dim3(32, 8), 0, stream>>>(x0, xf, xpad);
    zero_pads<<<80, 256, 0, stream>>>(xpad, midp);

    for (int l = 0; l < L; ++l) {
        cvt4_kernel<<<4 * C * C / 256, 256, 0, stream>>>(wq + (size_t)l * C * C, wk + (size_t)l * C * C,
                                                         wv + (size_t)l * C * C, wo + (size_t)l * C * C, wqkvo);
        cvtw1_kernel<<<FC * C * 3 / 256, 256, 0, stream>>>(w1 + (size_t)l * FC * C * 3, w1b);
        cvtw2_kernel<<<C * FC * 3 / 256, 256, 0, stream>>>(w2 + (size_t)l * C * FC * 3, w2b);

        // fused QKV projection: N=1536, K=512 -> qb, kb, vT
        gemm128<3, false, 1, 8, 1><<<dim3(1536 / 128, T / 128, B), 256, 0, stream>>>(
            xpad + C, (long)(T + 2) * C, C, wqkvo, 0, C,
            bq + l * C, bk + l * C, bv + l * C,
            (void*)qb, (void*)kb, (void*)vTb, 0, 0);

        attn_kernel<<<dim3(T / 128, H, B), 256, 0, stream>>>(qb, kb, vTb, rlk + (size_t)l * 9 * KC, yab);

        // O projection, split-K x2 -> f32 partials yf, yf2
        gemm128<0, false, 2, 8, 1><<<dim3(C / 128, T / 128, 2 * B), 256, 0, stream>>>(
            yab, (long)T * C, C, wqkvo + 3 * C * C, 0, C,
            bo + l * C, nullptr, nullptr,
            (void*)yf, (void*)yf2, nullptr, (long)T * C, C);

        add_ln<<<B * T, 256, 0, stream>>>(xf, yf, yf2, g1 + l * C, be1 + l * C, xpad);

        // FFN1: conv K=3 + bias + relu -> bf16 mid_pad rows 1..T
        gemm128<1, true, 1, 8, 3><<<dim3(FC / 128, T / 128, B), 256, 0, stream>>>(
            xpad, (long)(T + 2) * C, C, w1b, (long)FC * C, C,
            bb1 + l * FC, nullptr, nullptr,
            (void*)(midp + FC), nullptr, nullptr, (long)(T + 2) * FC, FC);

        // FFN2: conv K=3, split-K x2 -> f32 partials yf, yf2
        gemm128<0, false, 2, 32, 3><<<dim3(C / 128, T / 128, 2 * B), 256, 0, stream>>>(
            midp, (long)(T + 2) * FC, FC, w2b, (long)C * FC, FC,
            bb2 + l * C, nullptr, nullptr,
            (void*)yf, (void*)yf2, nullptr, (long)T * C, C);

        add_ln<<<B * T, 256, 0, stream>>>(xf, yf, yf2, g2 + l * C, be2 + l * C, xpad);
    }

    transpose_out<<<dim3(T / 32, C / 32, B), dim3(32, 8), 0, stream>>>(xf, (float*)d_out);
}

// Round 3
// 1313.957 us; speedup vs baseline: 2.0205x; 1.1746x over previous
//
#include <hip/hip_runtime.h>

// ---------------- problem constants ----------------
constexpr int L  = 6;
constexpr int C  = 512;
constexpr int FC = 2048;
constexpr int H  = 8;
constexpr int KC = 64;
constexpr int T  = 1024;
constexpr int B  = 4;
#define SCALE 0.125f   // 1/sqrt(KC)

typedef __bf16 bf16_t;
typedef __bf16 bf16x8 __attribute__((ext_vector_type(8)));
typedef float  f32x4  __attribute__((ext_vector_type(4)));

// ---------------- workspace layout (bytes) ----------------
constexpr size_t OFF_XF    = 0;                               // f32 [B][T][C]      8 MB
constexpr size_t OFF_YF    = OFF_XF   + (size_t)B*T*C*4;      // f32 [B][T][C]      8 MB (partial 0)
constexpr size_t OFF_XPAD  = OFF_YF   + (size_t)B*T*C*4;      // bf16 [B][T+2][C]
constexpr size_t OFF_Q     = OFF_XPAD + (size_t)B*(T+2)*C*2;  // bf16 [B][T][C]  (alias: f32 partial 1 spans Q+K)
constexpr size_t OFF_K     = OFF_Q    + (size_t)B*T*C*2;
constexpr size_t OFF_VT    = OFF_K    + (size_t)B*T*C*2;      // bf16 [B][C][T]  (alias: f32 partial 2 spans VT+YA)
constexpr size_t OFF_YA    = OFF_VT   + (size_t)B*T*C*2;      // bf16 [B][T][C]
constexpr size_t OFF_MID   = OFF_YA   + (size_t)B*T*C*2;      // bf16 [B][T+2][FC]  16 MB
constexpr size_t OFF_WQKVO = OFF_MID  + (size_t)B*(T+2)*FC*2; // bf16 [4][C][C]
constexpr size_t OFF_W1    = OFF_WQKVO+ (size_t)4*C*C*2;      // bf16 [3][FC][C]
constexpr size_t OFF_W2    = OFF_W1   + (size_t)3*FC*C*2;     // bf16 [3][C][FC]
// total ~69.3 MB

// ---------------- async global->LDS (16B/lane) ----------------
__device__ __forceinline__ void gload_lds16(const bf16_t* g, bf16_t* l) {
    __builtin_amdgcn_global_load_lds((const __attribute__((address_space(1))) void*)g,
                                     (__attribute__((address_space(3))) void*)l, 16, 0, 0);
}

// ---------------- conversion kernels ----------------
__global__ __launch_bounds__(256) void cvt4_kernel(const float* __restrict__ a,
                                                   const float* __restrict__ b,
                                                   const float* __restrict__ c,
                                                   const float* __restrict__ d,
                                                   bf16_t* __restrict__ out) {
    int i = blockIdx.x * 256 + threadIdx.x;      // 4*C*C
    int which = i >> 18;
    int idx   = i & ((1 << 18) - 1);
    const float* s = (which == 0) ? a : (which == 1) ? b : (which == 2) ? c : d;
    out[i] = (bf16_t)s[idx];
}

// coalesced-write transposing converters: out index linear in thread id
__global__ __launch_bounds__(256) void cvtw1_kernel(const float* __restrict__ w1, bf16_t* __restrict__ out) {
    int i = blockIdx.x * 256 + threadIdx.x;      // 3*FC*C,   out [3][FC][C]
    int j = i >> 20;                             // FC*C = 2^20
    int rem = i & ((1 << 20) - 1);
    int fc = rem >> 9, c = rem & 511;
    out[i] = (bf16_t)w1[fc * (C * 3) + c * 3 + j];
}

__global__ __launch_bounds__(256) void cvtw2_kernel(const float* __restrict__ w2, bf16_t* __restrict__ out) {
    int i = blockIdx.x * 256 + threadIdx.x;      // 3*C*FC,   out [3][C][FC]
    int j = i >> 20;                             // C*FC = 2^20
    int rem = i & ((1 << 20) - 1);
    int c = rem >> 11, fc = rem & 2047;
    out[i] = (bf16_t)w2[c * (FC * 3) + fc * 3 + j];
}

// ---------------- transpose in/out ----------------
__global__ __launch_bounds__(256) void transpose_in(const float* __restrict__ x0,
                                                    float* __restrict__ xf,
                                                    bf16_t* __restrict__ xpad) {
    __shared__ float tile[32][33];
    int b = blockIdx.z, t0 = blockIdx.x * 32, c0 = blockIdx.y * 32;
    int tx = threadIdx.x, ty = threadIdx.y;
#pragma unroll
    for (int j = 0; j < 4; ++j)
        tile[ty + j * 8][tx] = x0[((size_t)b * C + c0 + ty + j * 8) * T + t0 + tx];
    __syncthreads();
#pragma unroll
    for (int j = 0; j < 4; ++j) {
        float v = tile[tx][ty + j * 8];
        long t = t0 + ty + j * 8;
        xf[((size_t)b * T + t) * C + c0 + tx] = v;
        xpad[((size_t)b * (T + 2) + t + 1) * C + c0 + tx] = (bf16_t)v;
    }
}

__global__ __launch_bounds__(256) void transpose_out(const float* __restrict__ xf,
                                                     float* __restrict__ out) {
    __shared__ float tile[32][33];
    int b = blockIdx.z, t0 = blockIdx.x * 32, c0 = blockIdx.y * 32;
    int tx = threadIdx.x, ty = threadIdx.y;
#pragma unroll
    for (int j = 0; j < 4; ++j)
        tile[ty + j * 8][tx] = xf[((size_t)b * T + t0 + ty + j * 8) * C + c0 + tx];
    __syncthreads();
#pragma unroll
    for (int j = 0; j < 4; ++j)
        out[((size_t)b * C + c0 + ty + j * 8) * T + t0 + tx] = tile[tx][ty + j * 8];
}

// ---------------- zero conv pads ----------------
__global__ __launch_bounds__(256) void zero_pads(bf16_t* __restrict__ xpad, bf16_t* __restrict__ midp) {
    int i = blockIdx.x * 256 + threadIdx.x;
    if (i < 4096) {
        int b = i >> 10, r = (i >> 9) & 1, c = i & 511;
        xpad[((size_t)b * (T + 2) + (size_t)r * (T + 1)) * C + c] = (bf16_t)0.f;
    } else {
        int j = i - 4096;
        int b = j >> 12, r = (j >> 11) & 1, c = j & 2047;
        midp[((size_t)b * (T + 2) + (size_t)r * (T + 1)) * FC + c] = (bf16_t)0.f;
    }
}

// ---------------- residual + NP-partial sum + layernorm (channel dim) ----------------
template <int NP>
__global__ __launch_bounds__(256) void add_ln(float* __restrict__ x,
                                              const float* __restrict__ p0, const float* __restrict__ p1,
                                              const float* __restrict__ p2,
                                              const float* __restrict__ g, const float* __restrict__ be,
                                              bf16_t* __restrict__ xpad) {
    long bt = blockIdx.x;
    int tid = threadIdx.x;
    float* xr = x + bt * C;
    float v0 = xr[tid] + p0[bt * C + tid] + p1[bt * C + tid];
    float v1 = xr[tid + 256] + p0[bt * C + tid + 256] + p1[bt * C + tid + 256];
    if (NP == 3) { v0 += p2[bt * C + tid]; v1 += p2[bt * C + tid + 256]; }
    float s = v0 + v1, q = v0 * v0 + v1 * v1;
#pragma unroll
    for (int m = 1; m < 64; m <<= 1) { s += __shfl_xor(s, m); q += __shfl_xor(q, m); }
    __shared__ float ss[4], qq[4];
    int wid = tid >> 6;
    if ((tid & 63) == 0) { ss[wid] = s; qq[wid] = q; }
    __syncthreads();
    s = ss[0] + ss[1] + ss[2] + ss[3];
    q = qq[0] + qq[1] + qq[2] + qq[3];
    float mean = s * (1.f / C);
    float var = q * (1.f / C) - mean * mean;
    float rstd = rsqrtf(var + 1e-4f);
    float o0 = (v0 - mean) * rstd * g[tid] + be[tid];
    float o1 = (v1 - mean) * rstd * g[tid + 256] + be[tid + 256];
    xr[tid] = o0; xr[tid + 256] = o1;
    long b = bt >> 10, t = bt & (T - 1);
    bf16_t* xp = xpad + (b * (T + 2) + t + 1) * C;
    xp[tid] = (bf16_t)o0; xp[tid + 256] = (bf16_t)o1;
}

// ---------------- 128x128 GEMM, BK=64, global_load_lds + XOR-swizzled LDS ----------------
// LDS layout: LDS[row][v] (v = 16B unit 0..7) holds global[row][v ^ (row&7)]
// OUTMODE: 0 = f32 [M][N] split-partials (split0 +bias -> Dp, split1 -> D1p, split2 -> D2p)
//          1 = bf16 [M][N] (+bias, opt relu)
//          3 = QKV fused: col<512 -> Q (Dp), <1024 -> K (D1p), else V^T (D2p)
template <int OUTMODE, bool RELU, int NSPLIT, int IPT, int NTAPS>
__global__ __launch_bounds__(256) void gemm128(
    const bf16_t* __restrict__ A, long batchStrideA, int lda,
    const bf16_t* __restrict__ Bw, long tapStrideB, int ldb,
    const float* __restrict__ bias0, const float* __restrict__ bias1,
    const float* __restrict__ bias2,
    void* __restrict__ Dp, void* __restrict__ D1p, void* __restrict__ D2p,
    long batchStrideD, int ldd) {
    __shared__ bf16_t As[128 * 64];
    __shared__ bf16_t Bs[128 * 64];
    const int tid = threadIdx.x;
    const int lane = tid & 63, wid = tid >> 6;
    const int l15 = lane & 15, quad = lane >> 4;
    const int wy = wid >> 1, wx = wid & 1;
    const int nb = gridDim.z / NSPLIT;
    const int split = (NSPLIT > 1) ? ((int)blockIdx.z / nb) : 0;
    const int b = (int)blockIdx.z - split * nb;

    const bf16_t* Ab = A + (long)b * batchStrideA + (long)blockIdx.y * 128 * lda;
    const bf16_t* Bb = Bw + (long)blockIdx.x * 128 * ldb;

    const int lrow = lane >> 3;                        // row within 8-row chunk (== row&7)
    const int lcolsw = ((lane & 7) ^ lrow) * 8;        // swizzled source column (elems)

    f32x4 acc[4][4];
#pragma unroll
    for (int i = 0; i < 4; ++i)
#pragma unroll
        for (int j = 0; j < 4; ++j) acc[i][j] = (f32x4){0.f, 0.f, 0.f, 0.f};

    constexpr int itersAll = IPT * NTAPS;
    constexpr int per = itersAll / NSPLIT;
    const int it0 = split * per;

    for (int it = it0; it < it0 + per; ++it) {
        const int tap = (NTAPS == 1) ? 0 : (it / IPT);
        const int k0 = (it - tap * IPT) * 64;
        const bf16_t* At = Ab + (long)tap * lda + k0;
        const bf16_t* Bt = Bb + (long)tap * tapStrideB + k0;
        __syncthreads();
#pragma unroll
        for (int i = 0; i < 4; ++i) {
            int chunk = wid * 4 + i;
            int row = chunk * 8 + lrow;
            gload_lds16(At + (long)row * lda + lcolsw, As + chunk * 512 + lane * 8);
            gload_lds16(Bt + (long)row * ldb + lcolsw, Bs + chunk * 512 + lane * 8);
        }
        __syncthreads();
#pragma unroll
        for (int ks = 0; ks < 2; ++ks) {
            bf16x8 bfr[4], afr[4];
#pragma unroll
            for (int nt = 0; nt < 4; ++nt) {
                int row = wx * 64 + nt * 16 + l15;
                bfr[nt] = *(const bf16x8*)&Bs[row * 64 + (((ks * 4 + quad) ^ (l15 & 7)) * 8)];
            }
#pragma unroll
            for (int mt = 0; mt < 4; ++mt) {
                int row = wy * 64 + mt * 16 + l15;
                afr[mt] = *(const bf16x8*)&As[row * 64 + (((ks * 4 + quad) ^ (l15 & 7)) * 8)];
            }
#pragma unroll
            for (int mt = 0; mt < 4; ++mt)
#pragma unroll
                for (int nt = 0; nt < 4; ++nt)
                    acc[mt][nt] = __builtin_amdgcn_mfma_f32_16x16x32_bf16(afr[mt], bfr[nt], acc[mt][nt], 0, 0, 0);
        }
    }

    const long m0 = (long)blockIdx.y * 128 + wy * 64;
    const int n0g = (int)blockIdx.x * 128 + wx * 64;
#pragma unroll
    for (int mt = 0; mt < 4; ++mt) {
        long rowb = m0 + mt * 16 + quad * 4;
#pragma unroll
        for (int nt = 0; nt < 4; ++nt) {
            int col = n0g + nt * 16 + l15;
            if (OUTMODE == 0) {
                float bb = (split == 0) ? bias0[col] : 0.f;
                float* D = ((split == 0) ? (float*)Dp : (split == 1) ? (float*)D1p : (float*)D2p)
                           + (long)b * batchStrideD;
#pragma unroll
                for (int r = 0; r < 4; ++r) D[(rowb + r) * ldd + col] = acc[mt][nt][r] + bb;
            } else if (OUTMODE == 1) {
                float bb = bias0[col];
                bf16_t* D = (bf16_t*)Dp + (long)b * batchStrideD;
#pragma unroll
                for (int r = 0; r < 4; ++r) {
                    float v = acc[mt][nt][r] + bb;
                    if (RELU) v = fmaxf(v, 0.f);
                    D[(rowb + r) * ldd + col] = (bf16_t)v;
                }
            } else {  // QKV fused
                int which = col >> 9, cl = col & 511;
                const float* bp = (which == 0) ? bias0 : (which == 1) ? bias1 : bias2;
                float bb = bp[cl];
                if (which < 2) {
                    bf16_t* D = (bf16_t*)((which == 0) ? Dp : D1p) + (long)b * T * C;
#pragma unroll
                    for (int r = 0; r < 4; ++r) D[(rowb + r) * C + cl] = (bf16_t)(acc[mt][nt][r] + bb);
                } else {
                    bf16_t* D = (bf16_t*)D2p + (long)b * C * T;
                    union { bf16_t h[4]; uint2 u; } pk;
#pragma unroll
                    for (int r = 0; r < 4; ++r) pk.h[r] = (bf16_t)(acc[mt][nt][r] + bb);
                    *(uint2*)(D + (long)cl * T + rowb) = pk.u;
                }
            }
        }
    }
}

// ---------------- fused attention (flash-style, rel-pos via 9 clamped embeddings) ----------------
__global__ __launch_bounds__(256) void attn_kernel(const bf16_t* __restrict__ q,
                                                   const bf16_t* __restrict__ k,
                                                   const bf16_t* __restrict__ vT,
                                                   const float* __restrict__ relk,
                                                   bf16_t* __restrict__ y) {
    const int b = blockIdx.z, h = blockIdx.y;
    const int qt0 = blockIdx.x * 128;
    __shared__ bf16_t qp[128][72];
    __shared__ bf16_t kt[64][72];
    __shared__ bf16_t vt[64][72];
    __shared__ float  rl[128][12];

    const int tid = threadIdx.x;
    const int lane = tid & 63, wid = tid >> 6;
    const int l15 = lane & 15, quad = lane >> 4;

    const bf16_t* qbase = q + ((size_t)(b * T + qt0)) * C + h * 64;
#pragma unroll
    for (int i = 0; i < 4; ++i) {
        int idx = tid + i * 256;
        int r = idx >> 3, c = idx & 7;
        *(uint4*)&qp[r][c * 8] = *(const uint4*)(qbase + (long)r * C + c * 8);
    }
    __syncthreads();

    for (int i = tid; i < 128 * 9; i += 256) {
        int r = i / 9, j = i - r * 9;
        float acc = 0.f;
#pragma unroll
        for (int d = 0; d < 64; ++d) acc += (float)qp[r][d] * relk[j * 64 + d];
        rl[r][j] = acc * SCALE;
    }

    bf16x8 af[2][2];
#pragma unroll
    for (int mt = 0; mt < 2; ++mt)
#pragma unroll
        for (int ks = 0; ks < 2; ++ks)
            af[mt][ks] = *(const bf16x8*)&qp[wid * 32 + mt * 16 + l15][ks * 32 + quad * 8];

    float m_i[2][4], l_i[2][4];
    f32x4 o[2][4];
#pragma unroll
    for (int mt = 0; mt < 2; ++mt)
#pragma unroll
        for (int r = 0; r < 4; ++r) { m_i[mt][r] = -1e30f; l_i[mt][r] = 0.f; }
#pragma unroll
    for (int mt = 0; mt < 2; ++mt)
#pragma unroll
        for (int dn = 0; dn < 4; ++dn) o[mt][dn] = (f32x4){0.f, 0.f, 0.f, 0.f};

    for (int st = 0; st < T / 64; ++st) {
        __syncthreads();
        const bf16_t* kb = k + ((size_t)(b * T + st * 64)) * C + h * 64;
        const bf16_t* vb = vT + ((size_t)(b * C + h * 64)) * T + st * 64;
#pragma unroll
        for (int i = 0; i < 2; ++i) {
            int idx = tid + i * 256;
            int r = idx >> 3, c = idx & 7;
            *(uint4*)&kt[r][c * 8] = *(const uint4*)(kb + (long)r * C + c * 8);
        }
#pragma unroll
        for (int i = 0; i < 2; ++i) {
            int idx = tid + i * 256;
            int r = idx >> 3, c = idx & 7;
            *(uint4*)&vt[r][c * 8] = *(const uint4*)(vb + (long)r * T + c * 8);
        }
        __syncthreads();

        f32x4 sc4[2][4];
#pragma unroll
        for (int mt = 0; mt < 2; ++mt)
#pragma unroll
            for (int nt = 0; nt < 4; ++nt) {
                f32x4 a = (f32x4){0.f, 0.f, 0.f, 0.f};
#pragma unroll
                for (int ks = 0; ks < 2; ++ks) {
                    bf16x8 bfr = *(const bf16x8*)&kt[nt * 16 + l15][ks * 32 + quad * 8];
                    a = __builtin_amdgcn_mfma_f32_16x16x32_bf16(af[mt][ks], bfr, a, 0, 0, 0);
                }
                sc4[mt][nt] = a;
            }

#pragma unroll
        for (int mt = 0; mt < 2; ++mt)
#pragma unroll
            for (int nt = 0; nt < 4; ++nt)
#pragma unroll
                for (int r = 0; r < 4; ++r) {
                    int row = wid * 32 + mt * 16 + quad * 4 + r;
                    int tpos = qt0 + row;
                    int spos = st * 64 + nt * 16 + l15;
                    int j = spos - tpos + 4;
                    j = j < 0 ? 0 : (j > 8 ? 8 : j);
                    sc4[mt][nt][r] = sc4[mt][nt][r] * SCALE + rl[row][j];
                }

        float alpha[2][4];
#pragma unroll
        for (int mt = 0; mt < 2; ++mt)
#pragma unroll
            for (int r = 0; r < 4; ++r) {
                float mx = fmaxf(fmaxf(sc4[mt][0][r], sc4[mt][1][r]), fmaxf(sc4[mt][2][r], sc4[mt][3][r]));
#pragma unroll
                for (int d = 1; d < 16; d <<= 1) mx = fmaxf(mx, __shfl_xor(mx, d));
                float mn = fmaxf(m_i[mt][r], mx);
                alpha[mt][r] = __expf(m_i[mt][r] - mn);
                m_i[mt][r] = mn;
            }
#pragma unroll
        for (int mt = 0; mt < 2; ++mt)
#pragma unroll
            for (int r = 0; r < 4; ++r) {
                float rs = 0.f;
#pragma unroll
                for (int nt = 0; nt < 4; ++nt) {
                    float p = __expf(sc4[mt][nt][r] - m_i[mt][r]);
                    sc4[mt][nt][r] = p;
                    rs += p;
                }
#pragma unroll
                for (int d = 1; d < 16; d <<= 1) rs += __shfl_xor(rs, d);
                l_i[mt][r] = l_i[mt][r] * alpha[mt][r] + rs;
            }
#pragma unroll
        for (int mt = 0; mt < 2; ++mt)
#pragma unroll
            for (int dn = 0; dn < 4; ++dn)
#pragma unroll
                for (int r = 0; r < 4; ++r) o[mt][dn][r] *= alpha[mt][r];

#pragma unroll
        for (int mt = 0; mt < 2; ++mt)
#pragma unroll
            for (int nt = 0; nt < 4; ++nt)
#pragma unroll
                for (int r = 0; r < 4; ++r)
                    qp[wid * 32 + mt * 16 + quad * 4 + r][nt * 16 + l15] = (bf16_t)sc4[mt][nt][r];

#pragma unroll
        for (int mt = 0; mt < 2; ++mt) {
            bf16x8 pa[2];
#pragma unroll
            for (int ks = 0; ks < 2; ++ks)
                pa[ks] = *(const bf16x8*)&qp[wid * 32 + mt * 16 + l15][ks * 32 + quad * 8];
#pragma unroll
            for (int dn = 0; dn < 4; ++dn)
#pragma unroll
                for (int ks = 0; ks < 2; ++ks) {
                    bf16x8 vf = *(const bf16x8*)&vt[dn * 16 + l15][ks * 32 + quad * 8];
                    o[mt][dn] = __builtin_amdgcn_mfma_f32_16x16x32_bf16(pa[ks], vf, o[mt][dn], 0, 0, 0);
                }
        }
    }

    bf16_t* yb = y + ((size_t)(b * T + qt0)) * C + h * 64;
#pragma unroll
    for (int mt = 0; mt < 2; ++mt)
#pragma unroll
        for (int r = 0; r < 4; ++r) {
            float linv = 1.f / l_i[mt][r];
            int row = wid * 32 + mt * 16 + quad * 4 + r;
#pragma unroll
            for (int dn = 0; dn < 4; ++dn)
                yb[(long)row * C + dn * 16 + l15] = (bf16_t)(o[mt][dn][r] * linv);
        }
}

// ---------------- host launch ----------------
extern "C" void kernel_launch(void* const* d_in, const int* in_sizes, int n_in,
                              void* d_out, int out_size, void* d_ws, size_t ws_size,
                              hipStream_t stream) {
    const float* x0  = (const float*)d_in[0];
    const float* wq  = (const float*)d_in[1];
    const float* bq  = (const float*)d_in[2];
    const float* wk  = (const float*)d_in[3];
    const float* bk  = (const float*)d_in[4];
    const float* wv  = (const float*)d_in[5];
    const float* bv  = (const float*)d_in[6];
    const float* wo  = (const float*)d_in[7];
    const float* bo  = (const float*)d_in[8];
    const float* rlk = (const float*)d_in[9];
    const float* g1  = (const float*)d_in[10];
    const float* be1 = (const float*)d_in[11];
    const float* w1  = (const float*)d_in[12];
    const float* bb1 = (const float*)d_in[13];
    const float* w2  = (const float*)d_in[14];
    const float* bb2 = (const float*)d_in[15];
    const float* g2  = (const float*)d_in[16];
    const float* be2 = (const float*)d_in[17];

    char* ws = (char*)d_ws;
    float*  xf    = (float*)(ws + OFF_XF);
    float*  yf    = (float*)(ws + OFF_YF);
    float*  yf2   = (float*)(ws + OFF_Q);       // aliases Q+K (dead at use time)
    float*  yf3   = (float*)(ws + OFF_VT);      // aliases VT+YA (dead during FFN2)
    bf16_t* xpad  = (bf16_t*)(ws + OFF_XPAD);
    bf16_t* qb    = (bf16_t*)(ws + OFF_Q);
    bf16_t* kb    = (bf16_t*)(ws + OFF_K);
    bf16_t* vTb   = (bf16_t*)(ws + OFF_VT);
    bf16_t* yab   = (bf16_t*)(ws + OFF_YA);
    bf16_t* midp  = (bf16_t*)(ws + OFF_MID);
    bf16_t* wqkvo = (bf16_t*)(ws + OFF_WQKVO);
    bf16_t* w1b   = (bf16_t*)(ws + OFF_W1);
    bf16_t* w2b   = (bf16_t*)(ws + OFF_W2);

    transpose_in<<<dim3(T / 32, C / 32, B), dim3(32, 8), 0, stream>>>(x0, xf, xpad);
    zero_pads<<<80, 256, 0, stream>>>(xpad, midp);

    for (int l = 0; l < L; ++l) {
        cvt4_kernel<<<4 * C * C / 256, 256, 0, stream>>>(wq + (size_t)l * C * C, wk + (size_t)l * C * C,
                                                         wv + (size_t)l * C * C, wo + (size_t)l * C * C, wqkvo);
        cvtw1_kernel<<<3 * FC * C / 256, 256, 0, stream>>>(w1 + (size_t)l * FC * C * 3, w1b);
        cvtw2_kernel<<<3 * C * FC / 256, 256, 0, stream>>>(w2 + (size_t)l * C * FC * 3, w2b);

        // fused QKV projection: N=1536, K=512 -> qb, kb, vT
        gemm128<3, false, 1, 8, 1><<<dim3(1536 / 128, T / 128, B), 256, 0, stream>>>(
            xpad + C, (long)(T + 2) * C, C, wqkvo, 0, C,
            bq + l * C, bk + l * C, bv + l * C,
            (void*)qb, (void*)kb, (void*)vTb, 0, 0);

        attn_kernel<<<dim3(T / 128, H, B), 256, 0, stream>>>(qb, kb, vTb, rlk + (size_t)l * 9 * KC, yab);

        // O projection, split-K x2 -> f32 partials yf, yf2
        gemm128<0, false, 2, 8, 1><<<dim3(C / 128, T / 128, 2 * B), 256, 0, stream>>>(
            yab, (long)T * C, C, wqkvo + 3 * C * C, 0, C,
            bo + l * C, nullptr, nullptr,
            (void*)yf, (void*)yf2, nullptr, (long)T * C, C);

        add_ln<2><<<B * T, 256, 0, stream>>>(xf, yf, yf2, nullptr, g1 + l * C, be1 + l * C, xpad);

        // FFN1: conv K=3 + bias + relu -> bf16 mid_pad rows 1..T
        gemm128<1, true, 1, 8, 3><<<dim3(FC / 128, T / 128, B), 256, 0, stream>>>(
            xpad, (long)(T + 2) * C, C, w1b, (long)FC * C, C,
            bb1 + l * FC, nullptr, nullptr,
            (void*)(midp + FC), nullptr, nullptr, (long)(T + 2) * FC, FC);

        // FFN2: conv K=3, split-K x3 (tap-aligned) -> f32 partials yf, yf2, yf3
        gemm128<0, false, 3, 32, 3><<<dim3(C / 128, T / 128, 3 * B), 256, 0, stream>>>(
            midp, (long)(T + 2) * FC, FC, w2b, (long)C * FC, FC,
            bb2 + l * C, nullptr, nullptr,
            (void*)yf, (void*)yf2, (void*)yf3, (long)T * C, C);

        add_ln<3><<<B * T, 256, 0, stream>>>(xf, yf, yf2, yf3, g2 + l * C, be2 + l * C, xpad);
    }

    transpose_out<<<dim3(T / 32, C / 32, B), dim3(32, 8), 0, stream>>>(xf, (float*)d_out);
}

// Round 4
// 1305.800 us; speedup vs baseline: 2.0332x; 1.0062x over previous
//
#include <hip/hip_runtime.h>

// ---------------- problem constants ----------------
constexpr int L  = 6;
constexpr int C  = 512;
constexpr int FC = 2048;
constexpr int H  = 8;
constexpr int KC = 64;
constexpr int T  = 1024;
constexpr int B  = 4;
#define SCALE 0.125f   // 1/sqrt(KC)
#define LOG2E 1.4426950408889634f

typedef __bf16 bf16_t;
typedef __bf16 bf16x8 __attribute__((ext_vector_type(8)));
typedef float  f32x4  __attribute__((ext_vector_type(4)));

// ---------------- workspace layout (bytes) ----------------
constexpr size_t OFF_XF    = 0;                               // f32 [B][T][C]      8 MB
constexpr size_t OFF_YF    = OFF_XF   + (size_t)B*T*C*4;      // f32 [B][T][C]      8 MB (partial 0)
constexpr size_t OFF_XPAD  = OFF_YF   + (size_t)B*T*C*4;      // bf16 [B][T+2][C]
constexpr size_t OFF_Q     = OFF_XPAD + (size_t)B*(T+2)*C*2;  // bf16 [B][T][C]  (alias: f32 partial 1 spans Q+K)
constexpr size_t OFF_K     = OFF_Q    + (size_t)B*T*C*2;
constexpr size_t OFF_VT    = OFF_K    + (size_t)B*T*C*2;      // bf16 [B][C][T]  (alias: f32 partial 2 spans VT+YA)
constexpr size_t OFF_YA    = OFF_VT   + (size_t)B*T*C*2;      // bf16 [B][T][C]
constexpr size_t OFF_MID   = OFF_YA   + (size_t)B*T*C*2;      // bf16 [B][T+2][FC]  16 MB
constexpr size_t OFF_WQKVO = OFF_MID  + (size_t)B*(T+2)*FC*2; // bf16 [4][C][C]
constexpr size_t OFF_W1    = OFF_WQKVO+ (size_t)4*C*C*2;      // bf16 [3][FC][C]
constexpr size_t OFF_W2    = OFF_W1   + (size_t)3*FC*C*2;     // bf16 [3][C][FC]
// total ~69.3 MB

// ---------------- async global->LDS (16B/lane) ----------------
__device__ __forceinline__ void gload_lds16(const bf16_t* g, bf16_t* l) {
    __builtin_amdgcn_global_load_lds((const __attribute__((address_space(1))) void*)g,
                                     (__attribute__((address_space(3))) void*)l, 16, 0, 0);
}

// ---------------- conversion kernels ----------------
__global__ __launch_bounds__(256) void cvt4_kernel(const float* __restrict__ a,
                                                   const float* __restrict__ b,
                                                   const float* __restrict__ c,
                                                   const float* __restrict__ d,
                                                   bf16_t* __restrict__ out) {
    int i = blockIdx.x * 256 + threadIdx.x;      // 4*C*C
    int which = i >> 18;
    int idx   = i & ((1 << 18) - 1);
    const float* s = (which == 0) ? a : (which == 1) ? b : (which == 2) ? c : d;
    out[i] = (bf16_t)s[idx];
}

__global__ __launch_bounds__(256) void cvtw1_kernel(const float* __restrict__ w1, bf16_t* __restrict__ out) {
    int i = blockIdx.x * 256 + threadIdx.x;      // 3*FC*C,   out [3][FC][C]
    int j = i >> 20;
    int rem = i & ((1 << 20) - 1);
    int fc = rem >> 9, c = rem & 511;
    out[i] = (bf16_t)w1[fc * (C * 3) + c * 3 + j];
}

__global__ __launch_bounds__(256) void cvtw2_kernel(const float* __restrict__ w2, bf16_t* __restrict__ out) {
    int i = blockIdx.x * 256 + threadIdx.x;      // 3*C*FC,   out [3][C][FC]
    int j = i >> 20;
    int rem = i & ((1 << 20) - 1);
    int c = rem >> 11, fc = rem & 2047;
    out[i] = (bf16_t)w2[c * (FC * 3) + fc * 3 + j];
}

// ---------------- transpose in/out ----------------
__global__ __launch_bounds__(256) void transpose_in(const float* __restrict__ x0,
                                                    float* __restrict__ xf,
                                                    bf16_t* __restrict__ xpad) {
    __shared__ float tile[32][33];
    int b = blockIdx.z, t0 = blockIdx.x * 32, c0 = blockIdx.y * 32;
    int tx = threadIdx.x, ty = threadIdx.y;
#pragma unroll
    for (int j = 0; j < 4; ++j)
        tile[ty + j * 8][tx] = x0[((size_t)b * C + c0 + ty + j * 8) * T + t0 + tx];
    __syncthreads();
#pragma unroll
    for (int j = 0; j < 4; ++j) {
        float v = tile[tx][ty + j * 8];
        long t = t0 + ty + j * 8;
        xf[((size_t)b * T + t) * C + c0 + tx] = v;
        xpad[((size_t)b * (T + 2) + t + 1) * C + c0 + tx] = (bf16_t)v;
    }
}

__global__ __launch_bounds__(256) void transpose_out(const float* __restrict__ xf,
                                                     float* __restrict__ out) {
    __shared__ float tile[32][33];
    int b = blockIdx.z, t0 = blockIdx.x * 32, c0 = blockIdx.y * 32;
    int tx = threadIdx.x, ty = threadIdx.y;
#pragma unroll
    for (int j = 0; j < 4; ++j)
        tile[ty + j * 8][tx] = xf[((size_t)b * T + t0 + ty + j * 8) * C + c0 + tx];
    __syncthreads();
#pragma unroll
    for (int j = 0; j < 4; ++j)
        out[((size_t)b * C + c0 + ty + j * 8) * T + t0 + tx] = tile[tx][ty + j * 8];
}

// ---------------- zero conv pads ----------------
__global__ __launch_bounds__(256) void zero_pads(bf16_t* __restrict__ xpad, bf16_t* __restrict__ midp) {
    int i = blockIdx.x * 256 + threadIdx.x;
    if (i < 4096) {
        int b = i >> 10, r = (i >> 9) & 1, c = i & 511;
        xpad[((size_t)b * (T + 2) + (size_t)r * (T + 1)) * C + c] = (bf16_t)0.f;
    } else {
        int j = i - 4096;
        int b = j >> 12, r = (j >> 11) & 1, c = j & 2047;
        midp[((size_t)b * (T + 2) + (size_t)r * (T + 1)) * FC + c] = (bf16_t)0.f;
    }
}

// ---------------- residual + NP-partial sum + layernorm (channel dim) ----------------
template <int NP>
__global__ __launch_bounds__(256) void add_ln(float* __restrict__ x,
                                              const float* __restrict__ p0, const float* __restrict__ p1,
                                              const float* __restrict__ p2,
                                              const float* __restrict__ g, const float* __restrict__ be,
                                              bf16_t* __restrict__ xpad) {
    long bt = blockIdx.x;
    int tid = threadIdx.x;
    float* xr = x + bt * C;
    float v0 = xr[tid] + p0[bt * C + tid] + p1[bt * C + tid];
    float v1 = xr[tid + 256] + p0[bt * C + tid + 256] + p1[bt * C + tid + 256];
    if (NP == 3) { v0 += p2[bt * C + tid]; v1 += p2[bt * C + tid + 256]; }
    float s = v0 + v1, q = v0 * v0 + v1 * v1;
#pragma unroll
    for (int m = 1; m < 64; m <<= 1) { s += __shfl_xor(s, m); q += __shfl_xor(q, m); }
    __shared__ float ss[4], qq[4];
    int wid = tid >> 6;
    if ((tid & 63) == 0) { ss[wid] = s; qq[wid] = q; }
    __syncthreads();
    s = ss[0] + ss[1] + ss[2] + ss[3];
    q = qq[0] + qq[1] + qq[2] + qq[3];
    float mean = s * (1.f / C);
    float var = q * (1.f / C) - mean * mean;
    float rstd = rsqrtf(var + 1e-4f);
    float o0 = (v0 - mean) * rstd * g[tid] + be[tid];
    float o1 = (v1 - mean) * rstd * g[tid + 256] + be[tid + 256];
    xr[tid] = o0; xr[tid + 256] = o1;
    long b = bt >> 10, t = bt & (T - 1);
    bf16_t* xp = xpad + (b * (T + 2) + t + 1) * C;
    xp[tid] = (bf16_t)o0; xp[tid + 256] = (bf16_t)o1;
}

// ---------------- 128x128 GEMM, BK=64, global_load_lds + XOR-swizzled LDS ----------------
template <int OUTMODE, bool RELU, int NSPLIT, int IPT, int NTAPS>
__global__ __launch_bounds__(256) void gemm128(
    const bf16_t* __restrict__ A, long batchStrideA, int lda,
    const bf16_t* __restrict__ Bw, long tapStrideB, int ldb,
    const float* __restrict__ bias0, const float* __restrict__ bias1,
    const float* __restrict__ bias2,
    void* __restrict__ Dp, void* __restrict__ D1p, void* __restrict__ D2p,
    long batchStrideD, int ldd) {
    __shared__ bf16_t As[128 * 64];
    __shared__ bf16_t Bs[128 * 64];
    const int tid = threadIdx.x;
    const int lane = tid & 63, wid = tid >> 6;
    const int l15 = lane & 15, quad = lane >> 4;
    const int wy = wid >> 1, wx = wid & 1;
    const int nb = gridDim.z / NSPLIT;
    const int split = (NSPLIT > 1) ? ((int)blockIdx.z / nb) : 0;
    const int b = (int)blockIdx.z - split * nb;

    const bf16_t* Ab = A + (long)b * batchStrideA + (long)blockIdx.y * 128 * lda;
    const bf16_t* Bb = Bw + (long)blockIdx.x * 128 * ldb;

    const int lrow = lane >> 3;
    const int lcolsw = ((lane & 7) ^ lrow) * 8;

    f32x4 acc[4][4];
#pragma unroll
    for (int i = 0; i < 4; ++i)
#pragma unroll
        for (int j = 0; j < 4; ++j) acc[i][j] = (f32x4){0.f, 0.f, 0.f, 0.f};

    constexpr int itersAll = IPT * NTAPS;
    constexpr int per = itersAll / NSPLIT;
    const int it0 = split * per;

    for (int it = it0; it < it0 + per; ++it) {
        const int tap = (NTAPS == 1) ? 0 : (it / IPT);
        const int k0 = (it - tap * IPT) * 64;
        const bf16_t* At = Ab + (long)tap * lda + k0;
        const bf16_t* Bt = Bb + (long)tap * tapStrideB + k0;
        __syncthreads();
#pragma unroll
        for (int i = 0; i < 4; ++i) {
            int chunk = wid * 4 + i;
            int row = chunk * 8 + lrow;
            gload_lds16(At + (long)row * lda + lcolsw, As + chunk * 512 + lane * 8);
            gload_lds16(Bt + (long)row * ldb + lcolsw, Bs + chunk * 512 + lane * 8);
        }
        __syncthreads();
#pragma unroll
        for (int ks = 0; ks < 2; ++ks) {
            bf16x8 bfr[4], afr[4];
#pragma unroll
            for (int nt = 0; nt < 4; ++nt) {
                int row = wx * 64 + nt * 16 + l15;
                bfr[nt] = *(const bf16x8*)&Bs[row * 64 + (((ks * 4 + quad) ^ (l15 & 7)) * 8)];
            }
#pragma unroll
            for (int mt = 0; mt < 4; ++mt) {
                int row = wy * 64 + mt * 16 + l15;
                afr[mt] = *(const bf16x8*)&As[row * 64 + (((ks * 4 + quad) ^ (l15 & 7)) * 8)];
            }
#pragma unroll
            for (int mt = 0; mt < 4; ++mt)
#pragma unroll
                for (int nt = 0; nt < 4; ++nt)
                    acc[mt][nt] = __builtin_amdgcn_mfma_f32_16x16x32_bf16(afr[mt], bfr[nt], acc[mt][nt], 0, 0, 0);
        }
    }

    const long m0 = (long)blockIdx.y * 128 + wy * 64;
    const int n0g = (int)blockIdx.x * 128 + wx * 64;
#pragma unroll
    for (int mt = 0; mt < 4; ++mt) {
        long rowb = m0 + mt * 16 + quad * 4;
#pragma unroll
        for (int nt = 0; nt < 4; ++nt) {
            int col = n0g + nt * 16 + l15;
            if (OUTMODE == 0) {
                float bb = (split == 0) ? bias0[col] : 0.f;
                float* D = ((split == 0) ? (float*)Dp : (split == 1) ? (float*)D1p : (float*)D2p)
                           + (long)b * batchStrideD;
#pragma unroll
                for (int r = 0; r < 4; ++r) D[(rowb + r) * ldd + col] = acc[mt][nt][r] + bb;
            } else if (OUTMODE == 1) {
                float bb = bias0[col];
                bf16_t* D = (bf16_t*)Dp + (long)b * batchStrideD;
#pragma unroll
                for (int r = 0; r < 4; ++r) {
                    float v = acc[mt][nt][r] + bb;
                    if (RELU) v = fmaxf(v, 0.f);
                    D[(rowb + r) * ldd + col] = (bf16_t)v;
                }
            } else {  // QKV fused
                int which = col >> 9, cl = col & 511;
                const float* bp = (which == 0) ? bias0 : (which == 1) ? bias1 : bias2;
                float bb = bp[cl];
                if (which < 2) {
                    bf16_t* D = (bf16_t*)((which == 0) ? Dp : D1p) + (long)b * T * C;
#pragma unroll
                    for (int r = 0; r < 4; ++r) D[(rowb + r) * C + cl] = (bf16_t)(acc[mt][nt][r] + bb);
                } else {
                    bf16_t* D = (bf16_t*)D2p + (long)b * C * T;
                    union { bf16_t h[4]; uint2 u; } pk;
#pragma unroll
                    for (int r = 0; r < 4; ++r) pk.h[r] = (bf16_t)(acc[mt][nt][r] + bb);
                    *(uint2*)(D + (long)cl * T + rowb) = pk.u;
                }
            }
        }
    }
}

// ---------------- fused attention: 64-row Q tiles, double-buffered async K/V ----------------
// grid (T/64, H, B), 256 thr. Each wave owns 16 Q rows. exp2-domain softmax.
__global__ __launch_bounds__(256) void attn_kernel(const bf16_t* __restrict__ q,
                                                   const bf16_t* __restrict__ k,
                                                   const bf16_t* __restrict__ vT,
                                                   const float* __restrict__ relk,
                                                   bf16_t* __restrict__ y) {
    const int b = blockIdx.z, h = blockIdx.y;
    const int qt0 = blockIdx.x * 64;
    __shared__ bf16_t qps[64 * 72];      // swizzled Q [64][64] first, then P tile [64][72]
    __shared__ bf16_t ktb[2][64 * 64];   // swizzled K tiles [s][d]
    __shared__ bf16_t vtb[2][64 * 64];   // swizzled V^T tiles [d][s]
    __shared__ float  rl[64][12];        // rel logits (exp2 domain)

    const int tid = threadIdx.x;
    const int lane = tid & 63, wid = tid >> 6;
    const int l15 = lane & 15, quad = lane >> 4;
    const int lrow = lane >> 3;                // 0..7 row within 8-row chunk
    const int su   = ((lane & 7) ^ lrow) * 8;  // swizzled source elem offset

    // stage Q (8 chunks) + K/V tile 0, all async
    const bf16_t* qbase = q + ((size_t)(b * T + qt0)) * C + h * 64;
    const bf16_t* kbs = k + ((size_t)(b * T)) * C + h * 64;
    const bf16_t* vbs = vT + ((size_t)(b * C + h * 64)) * T;
#pragma unroll
    for (int i = 0; i < 2; ++i) {
        int chunk = wid * 2 + i;
        int row = chunk * 8 + lrow;
        gload_lds16(qbase + (long)row * C + su, qps + chunk * 512 + lane * 8);
        gload_lds16(kbs + (long)row * C + su, ktb[0] + chunk * 512 + lane * 8);
        gload_lds16(vbs + (long)row * T + su, vtb[0] + chunk * 512 + lane * 8);
    }
    __syncthreads();

    // rel logits: rl[r][j] = (SCALE*LOG2E) * q[r]·relk[j]   (reads swizzled qps)
    for (int i = tid; i < 64 * 9; i += 256) {
        int r = i / 9, j = i - r * 9;
        float acc = 0.f;
#pragma unroll
        for (int d = 0; d < 64; ++d)
            acc += (float)qps[r * 64 + ((d >> 3) ^ (r & 7)) * 8 + (d & 7)] * relk[j * 64 + d];
        rl[r][j] = acc * (SCALE * LOG2E);
    }

    // Q fragments: wave rows wid*16..wid*16+15
    bf16x8 af[2];
#pragma unroll
    for (int ks = 0; ks < 2; ++ks) {
        int r = wid * 16 + l15;
        af[ks] = *(const bf16x8*)&qps[r * 64 + (((ks * 4 + quad) ^ (r & 7)) * 8)];
    }

    float m_i[4], l_i[4];
    f32x4 o[4];
#pragma unroll
    for (int r = 0; r < 4; ++r) { m_i[r] = -1e30f; l_i[r] = 0.f; }
#pragma unroll
    for (int dn = 0; dn < 4; ++dn) o[dn] = (f32x4){0.f, 0.f, 0.f, 0.f};

    for (int st = 0; st < T / 64; ++st) {
        // barrier: stage(st) complete (compiler drains vmcnt), prior reads of the
        // other buffer finished, and (st==0) rl/af phase done so qps is free for P
        __syncthreads();
        if (st < T / 64 - 1) {
            const bf16_t* kb = kbs + (size_t)(st + 1) * 64 * C;
            const bf16_t* vb = vbs + (st + 1) * 64;
            bf16_t* kd = ktb[(st + 1) & 1];
            bf16_t* vd = vtb[(st + 1) & 1];
#pragma unroll
            for (int i = 0; i < 2; ++i) {
                int chunk = wid * 2 + i;
                int row = chunk * 8 + lrow;
                gload_lds16(kb + (long)row * C + su, kd + chunk * 512 + lane * 8);
                gload_lds16(vb + (long)row * T + su, vd + chunk * 512 + lane * 8);
            }
        }
        const bf16_t* ktc = ktb[st & 1];
        const bf16_t* vtc = vtb[st & 1];

        // scores: 16x64 per wave = 4 n-tiles
        f32x4 sc[4];
#pragma unroll
        for (int nt = 0; nt < 4; ++nt) {
            f32x4 a = (f32x4){0.f, 0.f, 0.f, 0.f};
#pragma unroll
            for (int ks = 0; ks < 2; ++ks) {
                int rr = nt * 16 + l15;
                bf16x8 bfr = *(const bf16x8*)&ktc[rr * 64 + (((ks * 4 + quad) ^ (l15 & 7)) * 8)];
                a = __builtin_amdgcn_mfma_f32_16x16x32_bf16(af[ks], bfr, a, 0, 0, 0);
            }
            sc[nt] = a;
        }

        // scale (exp2 domain) + rel bias
#pragma unroll
        for (int nt = 0; nt < 4; ++nt)
#pragma unroll
            for (int r = 0; r < 4; ++r) {
                int row = wid * 16 + quad * 4 + r;
                int j = (st * 64 + nt * 16 + l15) - (qt0 + row) + 4;
                j = j < 0 ? 0 : (j > 8 ? 8 : j);
                sc[nt][r] = sc[nt][r] * (SCALE * LOG2E) + rl[row][j];
            }

        // online softmax (base 2)
        float alpha[4];
#pragma unroll
        for (int r = 0; r < 4; ++r) {
            float mx = fmaxf(fmaxf(sc[0][r], sc[1][r]), fmaxf(sc[2][r], sc[3][r]));
#pragma unroll
            for (int d = 1; d < 16; d <<= 1) mx = fmaxf(mx, __shfl_xor(mx, d));
            float mn = fmaxf(m_i[r], mx);
            alpha[r] = exp2f(m_i[r] - mn);
            m_i[r] = mn;
        }
#pragma unroll
        for (int r = 0; r < 4; ++r) {
            float rs = 0.f;
#pragma unroll
            for (int nt = 0; nt < 4; ++nt) {
                float p = exp2f(sc[nt][r] - m_i[r]);
                sc[nt][r] = p;
                rs += p;
            }
#pragma unroll
            for (int d = 1; d < 16; d <<= 1) rs += __shfl_xor(rs, d);
            l_i[r] = l_i[r] * alpha[r] + rs;
        }
#pragma unroll
        for (int dn = 0; dn < 4; ++dn)
#pragma unroll
            for (int r = 0; r < 4; ++r) o[dn][r] *= alpha[r];

        // P through LDS (wave-private rows; C-layout -> A-layout)
#pragma unroll
        for (int nt = 0; nt < 4; ++nt)
#pragma unroll
            for (int r = 0; r < 4; ++r)
                qps[(wid * 16 + quad * 4 + r) * 72 + nt * 16 + l15] = (bf16_t)sc[nt][r];

        bf16x8 pa[2];
#pragma unroll
        for (int ks = 0; ks < 2; ++ks)
            pa[ks] = *(const bf16x8*)&qps[(wid * 16 + l15) * 72 + ks * 32 + quad * 8];
#pragma unroll
        for (int dn = 0; dn < 4; ++dn)
#pragma unroll
            for (int ks = 0; ks < 2; ++ks) {
                int rr = dn * 16 + l15;
                bf16x8 vf = *(const bf16x8*)&vtc[rr * 64 + (((ks * 4 + quad) ^ (l15 & 7)) * 8)];
                o[dn] = __builtin_amdgcn_mfma_f32_16x16x32_bf16(pa[ks], vf, o[dn], 0, 0, 0);
            }
    }

    // epilogue
    bf16_t* yb = y + ((size_t)(b * T + qt0)) * C + h * 64;
#pragma unroll
    for (int r = 0; r < 4; ++r) {
        float linv = 1.f / l_i[r];
        int row = wid * 16 + quad * 4 + r;
#pragma unroll
        for (int dn = 0; dn < 4; ++dn)
            yb[(long)row * C + dn * 16 + l15] = (bf16_t)(o[dn][r] * linv);
    }
}

// ---------------- host launch ----------------
extern "C" void kernel_launch(void* const* d_in, const int* in_sizes, int n_in,
                              void* d_out, int out_size, void* d_ws, size_t ws_size,
                              hipStream_t stream) {
    const float* x0  = (const float*)d_in[0];
    const float* wq  = (const float*)d_in[1];
    const float* bq  = (const float*)d_in[2];
    const float* wk  = (const float*)d_in[3];
    const float* bk  = (const float*)d_in[4];
    const float* wv  = (const float*)d_in[5];
    const float* bv  = (const float*)d_in[6];
    const float* wo  = (const float*)d_in[7];
    const float* bo  = (const float*)d_in[8];
    const float* rlk = (const float*)d_in[9];
    const float* g1  = (const float*)d_in[10];
    const float* be1 = (const float*)d_in[11];
    const float* w1  = (const float*)d_in[12];
    const float* bb1 = (const float*)d_in[13];
    const float* w2  = (const float*)d_in[14];
    const float* bb2 = (const float*)d_in[15];
    const float* g2  = (const float*)d_in[16];
    const float* be2 = (const float*)d_in[17];

    char* ws = (char*)d_ws;
    float*  xf    = (float*)(ws + OFF_XF);
    float*  yf    = (float*)(ws + OFF_YF);
    float*  yf2   = (float*)(ws + OFF_Q);       // aliases Q+K (dead at use time)
    float*  yf3   = (float*)(ws + OFF_VT);      // aliases VT+YA (dead during FFN2)
    bf16_t* xpad  = (bf16_t*)(ws + OFF_XPAD);
    bf16_t* qb    = (bf16_t*)(ws + OFF_Q);
    bf16_t* kb    = (bf16_t*)(ws + OFF_K);
    bf16_t* vTb   = (bf16_t*)(ws + OFF_VT);
    bf16_t* yab   = (bf16_t*)(ws + OFF_YA);
    bf16_t* midp  = (bf16_t*)(ws + OFF_MID);
    bf16_t* wqkvo = (bf16_t*)(ws + OFF_WQKVO);
    bf16_t* w1b   = (bf16_t*)(ws + OFF_W1);
    bf16_t* w2b   = (bf16_t*)(ws + OFF_W2);

    transpose_in<<<dim3(T / 32, C / 32, B), dim3(32, 8), 0, stream>>>(x0, xf, xpad);
    zero_pads<<<80, 256, 0, stream>>>(xpad, midp);

    for (int l = 0; l < L; ++l) {
        cvt4_kernel<<<4 * C * C / 256, 256, 0, stream>>>(wq + (size_t)l * C * C, wk + (size_t)l * C * C,
                                                         wv + (size_t)l * C * C, wo + (size_t)l * C * C, wqkvo);
        cvtw1_kernel<<<3 * FC * C / 256, 256, 0, stream>>>(w1 + (size_t)l * FC * C * 3, w1b);
        cvtw2_kernel<<<3 * C * FC / 256, 256, 0, stream>>>(w2 + (size_t)l * C * FC * 3, w2b);

        // fused QKV projection: N=1536, K=512 -> qb, kb, vT
        gemm128<3, false, 1, 8, 1><<<dim3(1536 / 128, T / 128, B), 256, 0, stream>>>(
            xpad + C, (long)(T + 2) * C, C, wqkvo, 0, C,
            bq + l * C, bk + l * C, bv + l * C,
            (void*)qb, (void*)kb, (void*)vTb, 0, 0);

        attn_kernel<<<dim3(T / 64, H, B), 256, 0, stream>>>(qb, kb, vTb, rlk + (size_t)l * 9 * KC, yab);

        // O projection, split-K x2 -> f32 partials yf, yf2
        gemm128<0, false, 2, 8, 1><<<dim3(C / 128, T / 128, 2 * B), 256, 0, stream>>>(
            yab, (long)T * C, C, wqkvo + 3 * C * C, 0, C,
            bo + l * C, nullptr, nullptr,
            (void*)yf, (void*)yf2, nullptr, (long)T * C, C);

        add_ln<2><<<B * T, 256, 0, stream>>>(xf, yf, yf2, nullptr, g1 + l * C, be1 + l * C, xpad);

        // FFN1: conv K=3 + bias + relu -> bf16 mid_pad rows 1..T
        gemm128<1, true, 1, 8, 3><<<dim3(FC / 128, T / 128, B), 256, 0, stream>>>(
            xpad, (long)(T + 2) * C, C, w1b, (long)FC * C, C,
            bb1 + l * FC, nullptr, nullptr,
            (void*)(midp + FC), nullptr, nullptr, (long)(T + 2) * FC, FC);

        // FFN2: conv K=3, split-K x3 (tap-aligned) -> f32 partials yf, yf2, yf3
        gemm128<0, false, 3, 32, 3><<<dim3(C / 128, T / 128, 3 * B), 256, 0, stream>>>(
            midp, (long)(T + 2) * FC, FC, w2b, (long)C * FC, FC,
            bb2 + l * C, nullptr, nullptr,
            (void*)yf, (void*)yf2, (void*)yf3, (long)T * C, C);

        add_ln<3><<<B * T, 256, 0, stream>>>(xf, yf, yf2, yf3, g2 + l * C, be2 + l * C, xpad);
    }

    transpose_out<<<dim3(T / 32, C / 32, B), dim3(32, 8), 0, stream>>>(xf, (float*)d_out);
}